// Round 9
// baseline (1550.038 us; speedup 1.0000x reference)
//
#include <hip/hip_runtime.h>
#include <cstdint>
#include <cstddef>

#define B_ROWS 16384
#define NEXP 16
#define HID 512
#define KTOT 4112   // 8*512 + 16
#define KPAD 4224   // multiple of 128 (2 K-tiles of 64 per iter)
#define EG 4        // experts per group
#define NGRP 4

typedef __attribute__((ext_vector_type(8))) short short8v;
typedef __attribute__((ext_vector_type(4))) float f32x4;

__device__ __forceinline__ float b2f(unsigned short s) {
  return __builtin_bit_cast(float, (unsigned)s << 16);
}
__device__ __forceinline__ unsigned short f2bf(float f) {
  unsigned u = __builtin_bit_cast(unsigned, f);
  return (unsigned short)((u + 0x7FFF + ((u >> 16) & 1)) >> 16);  // RNE
}

__device__ __forceinline__ void async16(void* lds, const void* g) {
  __builtin_amdgcn_global_load_lds((const __attribute__((address_space(1))) void*)g,
                                   (__attribute__((address_space(3))) void*)lds, 16, 0, 0);
}

// ---------------- pack combined -> bf16 [B][KPAD] ----------------
__global__ __launch_bounds__(256) void pack_kernel(
    const float* __restrict__ i0, const float* __restrict__ i1,
    const float* __restrict__ i2, const float* __restrict__ i3,
    const float* __restrict__ i4, const float* __restrict__ i5,
    const float* __restrict__ i6, const float* __restrict__ i7,
    const float* __restrict__ cate, unsigned short* __restrict__ comb)
{
  const long long idx = (long long)blockIdx.x * 256 + threadIdx.x;
  if (idx >= (long long)B_ROWS * (KPAD / 8)) return;
  const int b  = (int)(idx / (KPAD / 8));
  const int k8 = (int)(idx % (KPAD / 8));
  const int k  = k8 * 8;
  short8v v;
  if (k < 4096) {
    const int sel = k >> 9;
    const float* src = sel == 0 ? i0 : sel == 1 ? i1 : sel == 2 ? i2 : sel == 3 ? i3
                     : sel == 4 ? i4 : sel == 5 ? i5 : sel == 6 ? i6 : i7;
    src += (size_t)b * 512 + (k & 511);
    const float4 a = *(const float4*)(src);
    const float4 c = *(const float4*)(src + 4);
    v[0] = (short)f2bf(a.x); v[1] = (short)f2bf(a.y);
    v[2] = (short)f2bf(a.z); v[3] = (short)f2bf(a.w);
    v[4] = (short)f2bf(c.x); v[5] = (short)f2bf(c.y);
    v[6] = (short)f2bf(c.z); v[7] = (short)f2bf(c.w);
  } else if (k < KTOT) {
    const float* src = cate + (size_t)b * 16 + (k - 4096);
    const float4 a = *(const float4*)(src);
    const float4 c = *(const float4*)(src + 4);
    v[0] = (short)f2bf(a.x); v[1] = (short)f2bf(a.y);
    v[2] = (short)f2bf(a.z); v[3] = (short)f2bf(a.w);
    v[4] = (short)f2bf(c.x); v[5] = (short)f2bf(c.y);
    v[6] = (short)f2bf(c.z); v[7] = (short)f2bf(c.w);
  } else {
#pragma unroll
    for (int j = 0; j < 8; ++j) v[j] = 0;
  }
  *(short8v*)(comb + (size_t)b * KPAD + k) = v;
}

// ---------------- transpose f32 [E][Kin][N] -> bf16 [E][N][Kout] (zero-pad K) ----------------
__global__ __launch_bounds__(256) void transpose_kernel(
    const float* __restrict__ src, unsigned short* __restrict__ dst,
    int Kin, int N, int Kout)
{
  __shared__ unsigned short tile[64][68];
  const int e  = blockIdx.z;
  const int kt = blockIdx.x * 64;
  const int nt = blockIdx.y * 64;
  const int tx = threadIdx.x & 63, ty = threadIdx.x >> 6;
#pragma unroll
  for (int i = 0; i < 16; ++i) {
    const int kl = i * 4 + ty;
    const int kg = kt + kl;
    float v = (kg < Kin) ? src[((size_t)e * Kin + kg) * N + nt + tx] : 0.f;
    tile[kl][tx] = f2bf(v);
  }
  __syncthreads();
#pragma unroll
  for (int i = 0; i < 16; ++i) {
    const int nl = i * 4 + ty;
    const int kg = kt + tx;
    if (kg < Kout)
      dst[((size_t)e * N + nt + nl) * Kout + kg] = tile[tx][nl];
  }
}

// ---------------- gate ----------------
__global__ __launch_bounds__(256) void gate_kernel(
    const float* __restrict__ cate,
    const float* __restrict__ w1, const float* __restrict__ b1,
    const float* __restrict__ w2, const float* __restrict__ b2,
    float* __restrict__ gates)
{
  const int b = blockIdx.x * blockDim.x + threadIdx.x;
  if (b >= B_ROWS) return;
  float c[16];
  const float4* cp = (const float4*)(cate + (size_t)b * 16);
#pragma unroll
  for (int i = 0; i < 4; ++i) {
    float4 t = cp[i];
    c[i*4+0] = t.x; c[i*4+1] = t.y; c[i*4+2] = t.z; c[i*4+3] = t.w;
  }
  float h[8];
#pragma unroll
  for (int j = 0; j < 8; ++j) h[j] = b1[j];
#pragma unroll
  for (int i = 0; i < 16; ++i)
#pragma unroll
    for (int j = 0; j < 8; ++j) h[j] += c[i] * w1[i * 8 + j];
#pragma unroll
  for (int j = 0; j < 8; ++j) h[j] = h[j] > 0.f ? h[j] : 0.f;
  float lg[16];
#pragma unroll
  for (int k = 0; k < 16; ++k) lg[k] = b2[k];
#pragma unroll
  for (int j = 0; j < 8; ++j)
#pragma unroll
    for (int k = 0; k < 16; ++k) lg[k] += h[j] * w2[j * 16 + k];
  float mx = lg[0];
#pragma unroll
  for (int k = 1; k < 16; ++k) mx = fmaxf(mx, lg[k]);
  float s = 0.f;
#pragma unroll
  for (int k = 0; k < 16; ++k) { lg[k] = __expf(lg[k] - mx); s += lg[k]; }
  const float inv = 1.f / s;
  float4* gp = (float4*)(gates + (size_t)b * 16);
#pragma unroll
  for (int i = 0; i < 4; ++i)
    gp[i] = make_float4(lg[i*4]*inv, lg[i*4+1]*inv, lg[i*4+2]*inv, lg[i*4+3]*inv);
}

// ---------------- 256x256 8-phase bf16 GEMM, fragment-major LDS -----------
// Round-9 delta vs round-8 (ONE variable): LDS layout is FRAGMENT-MAJOR.
// Each 16x32-element MFMA fragment-chunk (1 KB) is stored so that lane l's
// 16B slice sits at chunk_base + l*16: ds_read_b128 is a perfectly
// sequential 64x16B wave read (provably conflict-free, max 128 B/cyc) and
// the address is one shared lane*16 VGPR + 16-bit immediate offsets.
// global_load_lds writes lane-sequential by HW; the per-lane GLOBAL source
// supplies the element that fragment slot needs: row = rg*16 + (lane&15),
// col = kt + kkc*32 + (lane>>4)*8. XOR swizzle deleted. Chunk id within a
// 32KB tile = rowgrp*2 + kk (rowgrp = tile_row/16, kk = K-half of 64).
// Instruction counts and the vmcnt ledger are identical to round 8.
#define SCHED0 __builtin_amdgcn_sched_barrier(0)
#define BAR do { SCHED0; __builtin_amdgcn_s_barrier(); SCHED0; } while(0)
#define WAITVM(n) do { asm volatile("s_waitcnt vmcnt(" #n ")" ::: "memory"); SCHED0; } while(0)

// stage 1 half-tile (128 rows = 16 chunks) of A or B: wave stages chunks
// h*16 + wave*2 + {0,1}; 2 global_load_lds per thread.
#define STAGE_T(Ts, Te, h, kt) do { \
  _Pragma("unroll") for (int i_ = 0; i_ < 2; ++i_) { \
    const int ch_ = (h)*16 + wave*2 + i_; \
    const int rg_ = ch_ >> 1, kkc_ = ch_ & 1; \
    async16(&Ts[ldsbuf + ch_*512 + lane*8], \
            Te + (size_t)(rg_*16 + fr)*K + (kt) + kkc_*32 + kq*8); \
  } } while(0)

#define STAGE_A(buf, h, kt) do { const int ldsbuf = (buf)*16384; STAGE_T(As, Ae, h, kt); } while(0)
#define STAGE_B(buf, h, kt) do { const int ldsbuf = (buf)*16384; STAGE_T(Bs, We, h, kt); } while(0)

#define LOAD_A(buf, MH) do { \
  _Pragma("unroll") for (int mi_ = 0; mi_ < 4; ++mi_) \
  _Pragma("unroll") for (int kk_ = 0; kk_ < 2; ++kk_) \
    af[mi_][kk_] = *(const short8v*)&As[(buf)*16384 + \
        ((wr*8 + (MH)*4 + mi_)*2 + kk_)*512 + lane*8]; \
  } while(0)

#define LOAD_B(buf, NH) do { \
  _Pragma("unroll") for (int ni_ = 0; ni_ < 2; ++ni_) \
  _Pragma("unroll") for (int kk_ = 0; kk_ < 2; ++kk_) \
    bf[NH][ni_][kk_] = *(const short8v*)&Bs[(buf)*16384 + \
        ((wc*4 + (NH)*2 + ni_)*2 + kk_)*512 + lane*8]; \
  } while(0)

#define QUAD(MH, NH) do { \
  __builtin_amdgcn_s_setprio(1); \
  _Pragma("unroll") for (int kk_ = 0; kk_ < 2; ++kk_) \
  _Pragma("unroll") for (int mi_ = 0; mi_ < 4; ++mi_) \
  _Pragma("unroll") for (int ni_ = 0; ni_ < 2; ++ni_) \
    acc[(MH)*4 + mi_][(NH)*2 + ni_] = __builtin_amdgcn_mfma_f32_16x16x32_bf16( \
        af[mi_][kk_], bf[NH][ni_][kk_], acc[(MH)*4 + mi_][(NH)*2 + ni_], 0, 0, 0); \
  __builtin_amdgcn_s_setprio(0); SCHED0; \
  } while(0)

__global__ __launch_bounds__(512, 2) void gemm8_kernel(
    const unsigned short* __restrict__ A, const unsigned short* __restrict__ Wt,
    const float* __restrict__ bias, unsigned short* __restrict__ Out,
    int K,
    long long strideA, long long strideW, long long strideB, long long strideO,
    const float* __restrict__ w3, float* __restrict__ eo_out)
{
  __shared__ unsigned short As[2 * 256 * 64];
  __shared__ unsigned short Bs[2 * 256 * 64];
  const int tid  = threadIdx.x;
  const int wave = tid >> 6, lane = tid & 63;
  const int wr = wave >> 2, wc = wave & 3;
  const int m0 = blockIdx.x * 256, n0 = blockIdx.y * 256;
  const int e  = blockIdx.z;
  const unsigned short* Ae = A + (size_t)e * strideA + (size_t)m0 * K;
  const unsigned short* We = Wt + (size_t)e * strideW + (size_t)n0 * K;
  const float* be = bias + (size_t)e * strideB;
  unsigned short* Oe = Out + (size_t)e * strideO;

  // unified lane geometry (staging source AND fragment reads)
  const int fr = lane & 15;     // row within 16-row fragment group
  const int kq = lane >> 4;     // 0..3 k-subgroup (8 bf16 each)

  f32x4 acc[8][4] = {};
  short8v af[4][2];
  short8v bf[2][2][2];

  // ---- prologue: B0,A0 -> buf0; B1 -> buf1 (12 loads), drain to last 4 ----
  STAGE_B(0, 0, 0); STAGE_B(0, 1, 0);
  STAGE_A(0, 0, 0); STAGE_A(0, 1, 0);
  STAGE_B(1, 0, 64); STAGE_B(1, 1, 64);
  WAITVM(4);   // drains B0,A0 -> buf0 fully staged; B1 (4 loads) in flight
  BAR;

  const int NITER = K / 128;
  for (int j = 0; j < NITER; ++j) {
    const bool st = (j < NITER - 1);
    const int kt_v  = j * 128 + 64;
    const int kt_u2 = j * 128 + 128;
    const int kt_v2 = j * 128 + 192;
    // P1 (boundary): read Q00(buf0) at top, compute it; then reads for P2
    LOAD_A(0, 0); LOAD_B(0, 0); SCHED0;
    QUAD(0, 0);
    LOAD_B(0, 1); SCHED0;
    STAGE_A(1, 0, kt_v);
    BAR;
    // P2: compute Q01; reads for P3 drain under it
    QUAD(0, 1);
    LOAD_A(0, 1); SCHED0;
    STAGE_A(1, 1, kt_v);
    BAR;
    // P3: compute Q10 (Q11 needs no new reads)
    QUAD(1, 0);
    if (st) STAGE_B(0, 0, kt_u2);
    BAR;
    // P4: compute Q11; counted vmcnt certifies buf1 fully landed
    QUAD(1, 1);
    if (st) STAGE_B(0, 1, kt_u2);
    if (st) { WAITVM(4); } else { WAITVM(0); }
    BAR;
    // P5 (boundary): read Q00(buf1) at top, compute it; then reads for P6
    LOAD_A(1, 0); LOAD_B(1, 0); SCHED0;
    QUAD(0, 0);
    LOAD_B(1, 1); SCHED0;
    if (st) STAGE_A(0, 0, kt_u2);
    BAR;
    // P6: compute Q01; reads for P7 drain under it
    QUAD(0, 1);
    LOAD_A(1, 1); SCHED0;
    if (st) STAGE_A(0, 1, kt_u2);
    BAR;
    // P7: compute Q10
    QUAD(1, 0);
    if (st) STAGE_B(1, 0, kt_v2);
    BAR;
    // P8: compute Q11; counted vmcnt certifies buf0 fully landed
    QUAD(1, 1);
    if (st) { STAGE_B(1, 1, kt_v2); WAITVM(4); }
    BAR;
  }

  // ---- epilogue ----
  if (w3 == nullptr) {
    // bias + relu + bf16 store
#pragma unroll
    for (int ni = 0; ni < 4; ++ni) {
      const int n = n0 + wc * 64 + ni * 16 + fr;
      const float bv = be[n];
#pragma unroll
      for (int mi = 0; mi < 8; ++mi) {
#pragma unroll
        for (int r = 0; r < 4; ++r) {
          const int m = m0 + wr * 128 + mi * 16 + kq * 4 + r;
          float v = acc[mi][ni][r] + bv;
          v = v > 0.f ? v : 0.f;
          Oe[(size_t)m * HID + n] = f2bf(v);
        }
      }
    }
  } else {
    // fused layer-3: p[m] = sum_n relu(acc+bias) * w3[n]; atomicAdd to eo
    const float* w3e = w3 + (size_t)e * HID;
    float bv[4], wv[4];
#pragma unroll
    for (int ni = 0; ni < 4; ++ni) {
      const int n = n0 + wc * 64 + ni * 16 + fr;
      bv[ni] = be[n];
      wv[ni] = w3e[n];
    }
    float* eoe = eo_out + (size_t)e * B_ROWS;
#pragma unroll
    for (int mi = 0; mi < 8; ++mi) {
#pragma unroll
      for (int r = 0; r < 4; ++r) {
        float p = 0.f;
#pragma unroll
        for (int ni = 0; ni < 4; ++ni) {
          float v = acc[mi][ni][r] + bv[ni];
          v = v > 0.f ? v : 0.f;
          p += v * wv[ni];
        }
        // reduce across the 16 fr-lanes (bits 0..3 of lane)
        p += __shfl_xor(p, 1, 64);
        p += __shfl_xor(p, 2, 64);
        p += __shfl_xor(p, 4, 64);
        p += __shfl_xor(p, 8, 64);
        if (fr == 0) {
          const int m = m0 + wr * 128 + mi * 16 + kq * 4 + r;
          atomicAdd(&eoe[m], p);
        }
      }
    }
  }
}

// ---------------- out[b] = sum_e gates[b][e] * (eo[e][b] + eb3[e]) ----------------
__global__ __launch_bounds__(256) void final_kernel(
    const float* __restrict__ gates, const float* __restrict__ eo,
    const float* __restrict__ eb3, float* __restrict__ out)
{
  const int b = blockIdx.x * blockDim.x + threadIdx.x;
  if (b >= B_ROWS) return;
  float s = 0.f;
#pragma unroll
  for (int e = 0; e < NEXP; ++e)
    s += gates[(size_t)b * 16 + e] * (eo[(size_t)e * B_ROWS + b] + eb3[e]);
  out[b] = s;
}

extern "C" void kernel_launch(void* const* d_in, const int* in_sizes, int n_in,
                              void* d_out, int out_size, void* d_ws, size_t ws_size,
                              hipStream_t stream)
{
  const float* user_emb = (const float*)d_in[0];
  const float* item_emb = (const float*)d_in[1];
  const float* f_i_1    = (const float*)d_in[2];
  const float* g_i_1    = (const float*)d_in[3];
  const float* f_i_2    = (const float*)d_in[4];
  const float* g_i_2    = (const float*)d_in[5];
  const float* f_i_3    = (const float*)d_in[6];
  const float* g_i_3    = (const float*)d_in[7];
  const float* cate     = (const float*)d_in[8];
  const float* gate_w1  = (const float*)d_in[9];
  const float* gate_b1  = (const float*)d_in[10];
  const float* gate_w2  = (const float*)d_in[11];
  const float* gate_b2  = (const float*)d_in[12];
  const float* ew1      = (const float*)d_in[13];
  const float* eb1      = (const float*)d_in[14];
  const float* ew2      = (const float*)d_in[15];
  const float* eb2      = (const float*)d_in[16];
  const float* ew3      = (const float*)d_in[17];
  const float* eb3      = (const float*)d_in[18];
  float* out = (float*)d_out;

  char* ws = (char*)d_ws;
  size_t off = 0;
  unsigned short* comb = (unsigned short*)(ws + off); off += (size_t)B_ROWS * KPAD * 2;
  unsigned short* w1t  = (unsigned short*)(ws + off); off += (size_t)NEXP * HID * KPAD * 2;
  unsigned short* w2t  = (unsigned short*)(ws + off); off += (size_t)NEXP * HID * HID * 2;
  unsigned short* h1   = (unsigned short*)(ws + off); off += (size_t)EG * B_ROWS * HID * 2;
  float* gates = (float*)(ws + off); off += (size_t)B_ROWS * NEXP * 4;
  float* eo    = (float*)(ws + off); off += (size_t)NEXP * B_ROWS * 4;

  // 0. zero eo accumulators (atomicAdd targets)
  hipMemsetAsync(eo, 0, (size_t)NEXP * B_ROWS * 4, stream);

  // 1. pack combined input (bf16, K zero-padded to 4224)
  {
    const long long total = (long long)B_ROWS * (KPAD / 8);
    const int blocks = (int)((total + 255) / 256);
    pack_kernel<<<blocks, 256, 0, stream>>>(user_emb, item_emb, f_i_1, g_i_1,
                                            f_i_2, g_i_2, f_i_3, g_i_3, cate, comb);
  }
  // 2. weight transposes to [E][N][K] bf16
  transpose_kernel<<<dim3(KPAD / 64, HID / 64, NEXP), 256, 0, stream>>>(ew1, w1t, KTOT, HID, KPAD);
  transpose_kernel<<<dim3(HID / 64, HID / 64, NEXP), 256, 0, stream>>>(ew2, w2t, HID, HID, HID);
  // 3. gates
  gate_kernel<<<B_ROWS / 256, 256, 0, stream>>>(cate, gate_w1, gate_b1, gate_w2, gate_b2, gates);

  // 4. expert groups: layer1 (K=4224) -> h1; layer2+layer3 fused (K=512) -> eo
  for (int g = 0; g < NGRP; ++g) {
    gemm8_kernel<<<dim3(B_ROWS / 256, HID / 256, EG), 512, 0, stream>>>(
        comb, w1t + (size_t)g * EG * HID * KPAD, eb1 + (size_t)g * EG * HID, h1,
        KPAD, 0LL, (long long)HID * KPAD, (long long)HID, (long long)B_ROWS * HID,
        nullptr, nullptr);
    gemm8_kernel<<<dim3(B_ROWS / 256, HID / 256, EG), 512, 0, stream>>>(
        h1, w2t + (size_t)g * EG * HID * HID, eb2 + (size_t)g * EG * HID, nullptr,
        HID, (long long)B_ROWS * HID, (long long)HID * HID, (long long)HID, 0LL,
        ew3 + (size_t)g * EG * HID, eo + (size_t)g * EG * B_ROWS);
  }
  // 5. combine
  final_kernel<<<B_ROWS / 256, 256, 0, stream>>>(gates, eo, eb3, out);
}

// Round 10
// 1318.681 us; speedup vs baseline: 1.1754x; 1.1754x over previous
//
#include <hip/hip_runtime.h>
#include <cstdint>
#include <cstddef>

#define B_ROWS 16384
#define NEXP 16
#define HID 512
#define KTOT 4112   // 8*512 + 16
#define KPAD 4224   // multiple of 128 (2 K-tiles of 64 per iter)
#define EG 4        // experts per group
#define NGRP 4

typedef __attribute__((ext_vector_type(8))) short short8v;
typedef __attribute__((ext_vector_type(4))) float f32x4;

__device__ __forceinline__ float b2f(unsigned short s) {
  return __builtin_bit_cast(float, (unsigned)s << 16);
}
__device__ __forceinline__ unsigned short f2bf(float f) {
  unsigned u = __builtin_bit_cast(unsigned, f);
  return (unsigned short)((u + 0x7FFF + ((u >> 16) & 1)) >> 16);  // RNE
}

__device__ __forceinline__ void async16(void* lds, const void* g) {
  __builtin_amdgcn_global_load_lds((const __attribute__((address_space(1))) void*)g,
                                   (__attribute__((address_space(3))) void*)lds, 16, 0, 0);
}

// ---------------- pack combined -> bf16 [B][KPAD] ----------------
__global__ __launch_bounds__(256) void pack_kernel(
    const float* __restrict__ i0, const float* __restrict__ i1,
    const float* __restrict__ i2, const float* __restrict__ i3,
    const float* __restrict__ i4, const float* __restrict__ i5,
    const float* __restrict__ i6, const float* __restrict__ i7,
    const float* __restrict__ cate, unsigned short* __restrict__ comb)
{
  const long long idx = (long long)blockIdx.x * 256 + threadIdx.x;
  if (idx >= (long long)B_ROWS * (KPAD / 8)) return;
  const int b  = (int)(idx / (KPAD / 8));
  const int k8 = (int)(idx % (KPAD / 8));
  const int k  = k8 * 8;
  short8v v;
  if (k < 4096) {
    const int sel = k >> 9;
    const float* src = sel == 0 ? i0 : sel == 1 ? i1 : sel == 2 ? i2 : sel == 3 ? i3
                     : sel == 4 ? i4 : sel == 5 ? i5 : sel == 6 ? i6 : i7;
    src += (size_t)b * 512 + (k & 511);
    const float4 a = *(const float4*)(src);
    const float4 c = *(const float4*)(src + 4);
    v[0] = (short)f2bf(a.x); v[1] = (short)f2bf(a.y);
    v[2] = (short)f2bf(a.z); v[3] = (short)f2bf(a.w);
    v[4] = (short)f2bf(c.x); v[5] = (short)f2bf(c.y);
    v[6] = (short)f2bf(c.z); v[7] = (short)f2bf(c.w);
  } else if (k < KTOT) {
    const float* src = cate + (size_t)b * 16 + (k - 4096);
    const float4 a = *(const float4*)(src);
    const float4 c = *(const float4*)(src + 4);
    v[0] = (short)f2bf(a.x); v[1] = (short)f2bf(a.y);
    v[2] = (short)f2bf(a.z); v[3] = (short)f2bf(a.w);
    v[4] = (short)f2bf(c.x); v[5] = (short)f2bf(c.y);
    v[6] = (short)f2bf(c.z); v[7] = (short)f2bf(c.w);
  } else {
#pragma unroll
    for (int j = 0; j < 8; ++j) v[j] = 0;
  }
  *(short8v*)(comb + (size_t)b * KPAD + k) = v;
}

// ---------------- transpose f32 [E][Kin][N] -> bf16 [E][N][Kout] (zero-pad K) ----------------
__global__ __launch_bounds__(256) void transpose_kernel(
    const float* __restrict__ src, unsigned short* __restrict__ dst,
    int Kin, int N, int Kout)
{
  __shared__ unsigned short tile[64][68];
  const int e  = blockIdx.z;
  const int kt = blockIdx.x * 64;
  const int nt = blockIdx.y * 64;
  const int tx = threadIdx.x & 63, ty = threadIdx.x >> 6;
#pragma unroll
  for (int i = 0; i < 16; ++i) {
    const int kl = i * 4 + ty;
    const int kg = kt + kl;
    float v = (kg < Kin) ? src[((size_t)e * Kin + kg) * N + nt + tx] : 0.f;
    tile[kl][tx] = f2bf(v);
  }
  __syncthreads();
#pragma unroll
  for (int i = 0; i < 16; ++i) {
    const int nl = i * 4 + ty;
    const int kg = kt + tx;
    if (kg < Kout)
      dst[((size_t)e * N + nt + nl) * Kout + kg] = tile[tx][nl];
  }
}

// ---------------- gate ----------------
__global__ __launch_bounds__(256) void gate_kernel(
    const float* __restrict__ cate,
    const float* __restrict__ w1, const float* __restrict__ b1,
    const float* __restrict__ w2, const float* __restrict__ b2,
    float* __restrict__ gates)
{
  const int b = blockIdx.x * blockDim.x + threadIdx.x;
  if (b >= B_ROWS) return;
  float c[16];
  const float4* cp = (const float4*)(cate + (size_t)b * 16);
#pragma unroll
  for (int i = 0; i < 4; ++i) {
    float4 t = cp[i];
    c[i*4+0] = t.x; c[i*4+1] = t.y; c[i*4+2] = t.z; c[i*4+3] = t.w;
  }
  float h[8];
#pragma unroll
  for (int j = 0; j < 8; ++j) h[j] = b1[j];
#pragma unroll
  for (int i = 0; i < 16; ++i)
#pragma unroll
    for (int j = 0; j < 8; ++j) h[j] += c[i] * w1[i * 8 + j];
#pragma unroll
  for (int j = 0; j < 8; ++j) h[j] = h[j] > 0.f ? h[j] : 0.f;
  float lg[16];
#pragma unroll
  for (int k = 0; k < 16; ++k) lg[k] = b2[k];
#pragma unroll
  for (int j = 0; j < 8; ++j)
#pragma unroll
    for (int k = 0; k < 16; ++k) lg[k] += h[j] * w2[j * 16 + k];
  float mx = lg[0];
#pragma unroll
  for (int k = 1; k < 16; ++k) mx = fmaxf(mx, lg[k]);
  float s = 0.f;
#pragma unroll
  for (int k = 0; k < 16; ++k) { lg[k] = __expf(lg[k] - mx); s += lg[k]; }
  const float inv = 1.f / s;
  float4* gp = (float4*)(gates + (size_t)b * 16);
#pragma unroll
  for (int i = 0; i < 4; ++i)
    gp[i] = make_float4(lg[i*4]*inv, lg[i*4+1]*inv, lg[i*4+2]*inv, lg[i*4+3]*inv);
}

// ---------------- 256x256 8-phase bf16 GEMM, zero-per-phase-VALU ----------
// Round-10 delta vs round-8 (ONE mechanism): all per-phase address VALU is
// eliminated. ds_reads use 4 precomputed per-thread byte-base pointers
// (A/B x kk0/kk1) + LITERAL offsets (compiler folds into ds offset:N imm,
// max 47104 < 65536). Staging uses 8 walked global pointers (one per 64-row
// chunk of A and B), advanced +256B per iter; each stage address is
// pointer + k-literal (128/256/384B, fits the 13-bit signed global imm).
// Theory: VALUBusy 16% (~213 cyc/phase/SIMD of re-derived addressing inside
// SCHED0 fences) sits directly on the lockstep critical path (2 waves/SIMD,
// pipe alternation) — the ~500cy/phase gap vs m201's 824cy serial model.
// Phase structure, barriers, vmcnt ledger identical to round 8.
#define SCHED0 __builtin_amdgcn_sched_barrier(0)
#define BAR do { SCHED0; __builtin_amdgcn_s_barrier(); SCHED0; } while(0)
#define WAITVM(n) do { asm volatile("s_waitcnt vmcnt(" #n ")" ::: "memory"); SCHED0; } while(0)

// stage one 64-row chunk pair (half-tile) via walked pointers + k literal
#define STAGE_A(buf, h, klit) do { \
  async16(&As[(buf)*16384 + ((h)*128 + wave*8)*64],      wpA##h##0 + (klit)); \
  async16(&As[(buf)*16384 + ((h)*128 + 64 + wave*8)*64], wpA##h##1 + (klit)); \
  } while(0)

#define STAGE_B(buf, h, klit) do { \
  async16(&Bs[(buf)*16384 + ((h)*128 + wave*8)*64],      wpB##h##0 + (klit)); \
  async16(&Bs[(buf)*16384 + ((h)*128 + 64 + wave*8)*64], wpB##h##1 + (klit)); \
  } while(0)

#define LOAD_A(buf, MH) do { \
  _Pragma("unroll") for (int mi_ = 0; mi_ < 4; ++mi_) { \
    af[mi_][0] = *(const short8v*)(pa0 + (buf)*32768 + (MH)*8192 + mi_*2048); \
    af[mi_][1] = *(const short8v*)(pa1 + (buf)*32768 + (MH)*8192 + mi_*2048); \
  } } while(0)

#define LOAD_B(buf, NH) do { \
  _Pragma("unroll") for (int ni_ = 0; ni_ < 2; ++ni_) { \
    bf[NH][ni_][0] = *(const short8v*)(pb0 + (buf)*32768 + (NH)*4096 + ni_*2048); \
    bf[NH][ni_][1] = *(const short8v*)(pb1 + (buf)*32768 + (NH)*4096 + ni_*2048); \
  } } while(0)

#define QUAD(MH, NH) do { \
  __builtin_amdgcn_s_setprio(1); \
  _Pragma("unroll") for (int kk_ = 0; kk_ < 2; ++kk_) \
  _Pragma("unroll") for (int mi_ = 0; mi_ < 4; ++mi_) \
  _Pragma("unroll") for (int ni_ = 0; ni_ < 2; ++ni_) \
    acc[(MH)*4 + mi_][(NH)*2 + ni_] = __builtin_amdgcn_mfma_f32_16x16x32_bf16( \
        af[mi_][kk_], bf[NH][ni_][kk_], acc[(MH)*4 + mi_][(NH)*2 + ni_], 0, 0, 0); \
  __builtin_amdgcn_s_setprio(0); SCHED0; \
  } while(0)

__global__ __launch_bounds__(512, 2) void gemm8_kernel(
    const unsigned short* __restrict__ A, const unsigned short* __restrict__ Wt,
    const float* __restrict__ bias, unsigned short* __restrict__ Out,
    int K,
    long long strideA, long long strideW, long long strideB, long long strideO,
    const float* __restrict__ w3, float* __restrict__ eo_out)
{
  __shared__ unsigned short As[2 * 256 * 64];
  __shared__ unsigned short Bs[2 * 256 * 64];
  const int tid  = threadIdx.x;
  const int wave = tid >> 6, lane = tid & 63;
  const int wr = wave >> 2, wc = wave & 3;
  const int m0 = blockIdx.x * 256, n0 = blockIdx.y * 256;
  const int e  = blockIdx.z;
  const unsigned short* Ae = A + (size_t)e * strideA + (size_t)m0 * K;
  const unsigned short* We = Wt + (size_t)e * strideW + (size_t)n0 * K;
  const float* be = bias + (size_t)e * strideB;
  unsigned short* Oe = Out + (size_t)e * strideO;

  // staging lane geometry
  const int rsub = lane >> 3;                 // 0..7 row within 8-row block
  const int ssw  = ((lane & 7) ^ rsub) * 8;   // pre-swizzled global k-slot
  // fragment lane geometry
  const int fr  = lane & 15;
  const int kq  = lane >> 4;                  // 0..3
  const int fr7 = fr & 7;

  // --- precomputed LDS read bases (bytes): everything else is a literal ---
  const char* pa0 = (const char*)As + wr*16384 + fr*128 + ((kq ^ fr7) << 4);
  const char* pa1 = (const char*)As + wr*16384 + fr*128 + (((4 + kq) ^ fr7) << 4);
  const char* pb0 = (const char*)Bs + wc*8192  + fr*128 + ((kq ^ fr7) << 4);
  const char* pb1 = (const char*)Bs + wc*8192  + fr*128 + (((4 + kq) ^ fr7) << 4);

  // --- walked global staging pointers (one per 64-row chunk), +128 els/iter ---
  const unsigned short* wpA00 = Ae + (size_t)(      wave*8 + rsub) * K + ssw;
  const unsigned short* wpA01 = Ae + (size_t)( 64 + wave*8 + rsub) * K + ssw;
  const unsigned short* wpA10 = Ae + (size_t)(128 + wave*8 + rsub) * K + ssw;
  const unsigned short* wpA11 = Ae + (size_t)(192 + wave*8 + rsub) * K + ssw;
  const unsigned short* wpB00 = We + (size_t)(      wave*8 + rsub) * K + ssw;
  const unsigned short* wpB01 = We + (size_t)( 64 + wave*8 + rsub) * K + ssw;
  const unsigned short* wpB10 = We + (size_t)(128 + wave*8 + rsub) * K + ssw;
  const unsigned short* wpB11 = We + (size_t)(192 + wave*8 + rsub) * K + ssw;

  f32x4 acc[8][4] = {};
  short8v af[4][2];
  short8v bf[2][2][2];

  // ---- prologue: B0,A0 -> buf0; B1 -> buf1 (12 loads), drain to last 4 ----
  STAGE_B(0, 0, 0); STAGE_B(0, 1, 0);
  STAGE_A(0, 0, 0); STAGE_A(0, 1, 0);
  STAGE_B(1, 0, 64); STAGE_B(1, 1, 64);
  WAITVM(4);   // drains B0,A0 -> buf0 fully staged; B1 (4 loads) in flight
  BAR;

  const int NITER = K / 128;
  for (int j = 0; j < NITER; ++j) {
    const bool st = (j < NITER - 1);
    // P1 (boundary): read Q00(buf0) at top, compute it; then reads for P2
    LOAD_A(0, 0); LOAD_B(0, 0); SCHED0;
    QUAD(0, 0);
    LOAD_B(0, 1); SCHED0;
    STAGE_A(1, 0, 64);
    BAR;
    // P2: compute Q01; reads for P3 drain under it
    QUAD(0, 1);
    LOAD_A(0, 1); SCHED0;
    STAGE_A(1, 1, 64);
    BAR;
    // P3: compute Q10 (Q11 needs no new reads)
    QUAD(1, 0);
    if (st) STAGE_B(0, 0, 128);
    BAR;
    // P4: compute Q11; counted vmcnt certifies buf1 fully landed
    QUAD(1, 1);
    if (st) STAGE_B(0, 1, 128);
    if (st) { WAITVM(4); } else { WAITVM(0); }
    BAR;
    // P5 (boundary): read Q00(buf1) at top, compute it; then reads for P6
    LOAD_A(1, 0); LOAD_B(1, 0); SCHED0;
    QUAD(0, 0);
    LOAD_B(1, 1); SCHED0;
    if (st) STAGE_A(0, 0, 128);
    BAR;
    // P6: compute Q01; reads for P7 drain under it
    QUAD(0, 1);
    LOAD_A(1, 1); SCHED0;
    if (st) STAGE_A(0, 1, 128);
    BAR;
    // P7: compute Q10
    QUAD(1, 0);
    if (st) STAGE_B(1, 0, 192);
    BAR;
    // P8: compute Q11; counted vmcnt certifies buf0 fully landed
    QUAD(1, 1);
    if (st) { STAGE_B(1, 1, 192); WAITVM(4); }
    BAR;
    // advance staging pointers one iter (2 K-tiles = 128 elements)
    wpA00 += 128; wpA01 += 128; wpA10 += 128; wpA11 += 128;
    wpB00 += 128; wpB01 += 128; wpB10 += 128; wpB11 += 128;
  }

  // ---- epilogue ----
  if (w3 == nullptr) {
    // bias + relu + bf16 store
#pragma unroll
    for (int ni = 0; ni < 4; ++ni) {
      const int n = n0 + wc * 64 + ni * 16 + fr;
      const float bv = be[n];
#pragma unroll
      for (int mi = 0; mi < 8; ++mi) {
#pragma unroll
        for (int r = 0; r < 4; ++r) {
          const int m = m0 + wr * 128 + mi * 16 + kq * 4 + r;
          float v = acc[mi][ni][r] + bv;
          v = v > 0.f ? v : 0.f;
          Oe[(size_t)m * HID + n] = f2bf(v);
        }
      }
    }
  } else {
    // fused layer-3: p[m] = sum_n relu(acc+bias) * w3[n]; atomicAdd to eo
    const float* w3e = w3 + (size_t)e * HID;
    float bv[4], wv[4];
#pragma unroll
    for (int ni = 0; ni < 4; ++ni) {
      const int n = n0 + wc * 64 + ni * 16 + fr;
      bv[ni] = be[n];
      wv[ni] = w3e[n];
    }
    float* eoe = eo_out + (size_t)e * B_ROWS;
#pragma unroll
    for (int mi = 0; mi < 8; ++mi) {
#pragma unroll
      for (int r = 0; r < 4; ++r) {
        float p = 0.f;
#pragma unroll
        for (int ni = 0; ni < 4; ++ni) {
          float v = acc[mi][ni][r] + bv[ni];
          v = v > 0.f ? v : 0.f;
          p += v * wv[ni];
        }
        // reduce across the 16 fr-lanes (bits 0..3 of lane)
        p += __shfl_xor(p, 1, 64);
        p += __shfl_xor(p, 2, 64);
        p += __shfl_xor(p, 4, 64);
        p += __shfl_xor(p, 8, 64);
        if (fr == 0) {
          const int m = m0 + wr * 128 + mi * 16 + kq * 4 + r;
          atomicAdd(&eoe[m], p);
        }
      }
    }
  }
}

// ---------------- out[b] = sum_e gates[b][e] * (eo[e][b] + eb3[e]) ----------------
__global__ __launch_bounds__(256) void final_kernel(
    const float* __restrict__ gates, const float* __restrict__ eo,
    const float* __restrict__ eb3, float* __restrict__ out)
{
  const int b = blockIdx.x * blockDim.x + threadIdx.x;
  if (b >= B_ROWS) return;
  float s = 0.f;
#pragma unroll
  for (int e = 0; e < NEXP; ++e)
    s += gates[(size_t)b * 16 + e] * (eo[(size_t)e * B_ROWS + b] + eb3[e]);
  out[b] = s;
}

extern "C" void kernel_launch(void* const* d_in, const int* in_sizes, int n_in,
                              void* d_out, int out_size, void* d_ws, size_t ws_size,
                              hipStream_t stream)
{
  const float* user_emb = (const float*)d_in[0];
  const float* item_emb = (const float*)d_in[1];
  const float* f_i_1    = (const float*)d_in[2];
  const float* g_i_1    = (const float*)d_in[3];
  const float* f_i_2    = (const float*)d_in[4];
  const float* g_i_2    = (const float*)d_in[5];
  const float* f_i_3    = (const float*)d_in[6];
  const float* g_i_3    = (const float*)d_in[7];
  const float* cate     = (const float*)d_in[8];
  const float* gate_w1  = (const float*)d_in[9];
  const float* gate_b1  = (const float*)d_in[10];
  const float* gate_w2  = (const float*)d_in[11];
  const float* gate_b2  = (const float*)d_in[12];
  const float* ew1      = (const float*)d_in[13];
  const float* eb1      = (const float*)d_in[14];
  const float* ew2      = (const float*)d_in[15];
  const float* eb2      = (const float*)d_in[16];
  const float* ew3      = (const float*)d_in[17];
  const float* eb3      = (const float*)d_in[18];
  float* out = (float*)d_out;

  char* ws = (char*)d_ws;
  size_t off = 0;
  unsigned short* comb = (unsigned short*)(ws + off); off += (size_t)B_ROWS * KPAD * 2;
  unsigned short* w1t  = (unsigned short*)(ws + off); off += (size_t)NEXP * HID * KPAD * 2;
  unsigned short* w2t  = (unsigned short*)(ws + off); off += (size_t)NEXP * HID * HID * 2;
  unsigned short* h1   = (unsigned short*)(ws + off); off += (size_t)EG * B_ROWS * HID * 2;
  float* gates = (float*)(ws + off); off += (size_t)B_ROWS * NEXP * 4;
  float* eo    = (float*)(ws + off); off += (size_t)NEXP * B_ROWS * 4;

  // 0. zero eo accumulators (atomicAdd targets)
  hipMemsetAsync(eo, 0, (size_t)NEXP * B_ROWS * 4, stream);

  // 1. pack combined input (bf16, K zero-padded to 4224)
  {
    const long long total = (long long)B_ROWS * (KPAD / 8);
    const int blocks = (int)((total + 255) / 256);
    pack_kernel<<<blocks, 256, 0, stream>>>(user_emb, item_emb, f_i_1, g_i_1,
                                            f_i_2, g_i_2, f_i_3, g_i_3, cate, comb);
  }
  // 2. weight transposes to [E][N][K] bf16
  transpose_kernel<<<dim3(KPAD / 64, HID / 64, NEXP), 256, 0, stream>>>(ew1, w1t, KTOT, HID, KPAD);
  transpose_kernel<<<dim3(HID / 64, HID / 64, NEXP), 256, 0, stream>>>(ew2, w2t, HID, HID, HID);
  // 3. gates
  gate_kernel<<<B_ROWS / 256, 256, 0, stream>>>(cate, gate_w1, gate_b1, gate_w2, gate_b2, gates);

  // 4. expert groups: layer1 (K=4224) -> h1; layer2+layer3 fused (K=512) -> eo
  for (int g = 0; g < NGRP; ++g) {
    gemm8_kernel<<<dim3(B_ROWS / 256, HID / 256, EG), 512, 0, stream>>>(
        comb, w1t + (size_t)g * EG * HID * KPAD, eb1 + (size_t)g * EG * HID, h1,
        KPAD, 0LL, (long long)HID * KPAD, (long long)HID, (long long)B_ROWS * HID,
        nullptr, nullptr);
    gemm8_kernel<<<dim3(B_ROWS / 256, HID / 256, EG), 512, 0, stream>>>(
        h1, w2t + (size_t)g * EG * HID * HID, eb2 + (size_t)g * EG * HID, nullptr,
        HID, (long long)B_ROWS * HID, (long long)HID * HID, (long long)HID, 0LL,
        ew3 + (size_t)g * EG * HID, eo + (size_t)g * EG * B_ROWS);
  }
  // 5. combine
  final_kernel<<<B_ROWS / 256, 256, 0, stream>>>(gates, eo, eb3, out);
}

// Round 11
// 1310.549 us; speedup vs baseline: 1.1827x; 1.0062x over previous
//
#include <hip/hip_runtime.h>
#include <cstdint>
#include <cstddef>

#define B_ROWS 16384
#define NEXP 16
#define HID 512
#define KTOT 4112   // 8*512 + 16
#define KPAD 4224   // multiple of 128 (2 K-tiles of 64 per iter)
#define EG 4        // experts per group
#define NGRP 4

typedef __attribute__((ext_vector_type(8))) short short8v;
typedef __attribute__((ext_vector_type(4))) float f32x4;

__device__ __forceinline__ float b2f(unsigned short s) {
  return __builtin_bit_cast(float, (unsigned)s << 16);
}
__device__ __forceinline__ unsigned short f2bf(float f) {
  unsigned u = __builtin_bit_cast(unsigned, f);
  return (unsigned short)((u + 0x7FFF + ((u >> 16) & 1)) >> 16);  // RNE
}

__device__ __forceinline__ void async16(void* lds, const void* g) {
  __builtin_amdgcn_global_load_lds((const __attribute__((address_space(1))) void*)g,
                                   (__attribute__((address_space(3))) void*)lds, 16, 0, 0);
}

// ---------------- pack combined -> bf16 [B][KPAD] ----------------
__global__ __launch_bounds__(256) void pack_kernel(
    const float* __restrict__ i0, const float* __restrict__ i1,
    const float* __restrict__ i2, const float* __restrict__ i3,
    const float* __restrict__ i4, const float* __restrict__ i5,
    const float* __restrict__ i6, const float* __restrict__ i7,
    const float* __restrict__ cate, unsigned short* __restrict__ comb)
{
  const long long idx = (long long)blockIdx.x * 256 + threadIdx.x;
  if (idx >= (long long)B_ROWS * (KPAD / 8)) return;
  const int b  = (int)(idx / (KPAD / 8));
  const int k8 = (int)(idx % (KPAD / 8));
  const int k  = k8 * 8;
  short8v v;
  if (k < 4096) {
    const int sel = k >> 9;
    const float* src = sel == 0 ? i0 : sel == 1 ? i1 : sel == 2 ? i2 : sel == 3 ? i3
                     : sel == 4 ? i4 : sel == 5 ? i5 : sel == 6 ? i6 : i7;
    src += (size_t)b * 512 + (k & 511);
    const float4 a = *(const float4*)(src);
    const float4 c = *(const float4*)(src + 4);
    v[0] = (short)f2bf(a.x); v[1] = (short)f2bf(a.y);
    v[2] = (short)f2bf(a.z); v[3] = (short)f2bf(a.w);
    v[4] = (short)f2bf(c.x); v[5] = (short)f2bf(c.y);
    v[6] = (short)f2bf(c.z); v[7] = (short)f2bf(c.w);
  } else if (k < KTOT) {
    const float* src = cate + (size_t)b * 16 + (k - 4096);
    const float4 a = *(const float4*)(src);
    const float4 c = *(const float4*)(src + 4);
    v[0] = (short)f2bf(a.x); v[1] = (short)f2bf(a.y);
    v[2] = (short)f2bf(a.z); v[3] = (short)f2bf(a.w);
    v[4] = (short)f2bf(c.x); v[5] = (short)f2bf(c.y);
    v[6] = (short)f2bf(c.z); v[7] = (short)f2bf(c.w);
  } else {
#pragma unroll
    for (int j = 0; j < 8; ++j) v[j] = 0;
  }
  *(short8v*)(comb + (size_t)b * KPAD + k) = v;
}

// ---------------- transpose f32 [E][Kin][N] -> bf16 [E][N][Kout] (zero-pad K) ----------------
__global__ __launch_bounds__(256) void transpose_kernel(
    const float* __restrict__ src, unsigned short* __restrict__ dst,
    int Kin, int N, int Kout)
{
  __shared__ unsigned short tile[64][68];
  const int e  = blockIdx.z;
  const int kt = blockIdx.x * 64;
  const int nt = blockIdx.y * 64;
  const int tx = threadIdx.x & 63, ty = threadIdx.x >> 6;
#pragma unroll
  for (int i = 0; i < 16; ++i) {
    const int kl = i * 4 + ty;
    const int kg = kt + kl;
    float v = (kg < Kin) ? src[((size_t)e * Kin + kg) * N + nt + tx] : 0.f;
    tile[kl][tx] = f2bf(v);
  }
  __syncthreads();
#pragma unroll
  for (int i = 0; i < 16; ++i) {
    const int nl = i * 4 + ty;
    const int kg = kt + tx;
    if (kg < Kout)
      dst[((size_t)e * N + nt + nl) * Kout + kg] = tile[tx][nl];
  }
}

// ---------------- gate ----------------
__global__ __launch_bounds__(256) void gate_kernel(
    const float* __restrict__ cate,
    const float* __restrict__ w1, const float* __restrict__ b1,
    const float* __restrict__ w2, const float* __restrict__ b2,
    float* __restrict__ gates)
{
  const int b = blockIdx.x * blockDim.x + threadIdx.x;
  if (b >= B_ROWS) return;
  float c[16];
  const float4* cp = (const float4*)(cate + (size_t)b * 16);
#pragma unroll
  for (int i = 0; i < 4; ++i) {
    float4 t = cp[i];
    c[i*4+0] = t.x; c[i*4+1] = t.y; c[i*4+2] = t.z; c[i*4+3] = t.w;
  }
  float h[8];
#pragma unroll
  for (int j = 0; j < 8; ++j) h[j] = b1[j];
#pragma unroll
  for (int i = 0; i < 16; ++i)
#pragma unroll
    for (int j = 0; j < 8; ++j) h[j] += c[i] * w1[i * 8 + j];
#pragma unroll
  for (int j = 0; j < 8; ++j) h[j] = h[j] > 0.f ? h[j] : 0.f;
  float lg[16];
#pragma unroll
  for (int k = 0; k < 16; ++k) lg[k] = b2[k];
#pragma unroll
  for (int j = 0; j < 8; ++j)
#pragma unroll
    for (int k = 0; k < 16; ++k) lg[k] += h[j] * w2[j * 16 + k];
  float mx = lg[0];
#pragma unroll
  for (int k = 1; k < 16; ++k) mx = fmaxf(mx, lg[k]);
  float s = 0.f;
#pragma unroll
  for (int k = 0; k < 16; ++k) { lg[k] = __expf(lg[k] - mx); s += lg[k]; }
  const float inv = 1.f / s;
  float4* gp = (float4*)(gates + (size_t)b * 16);
#pragma unroll
  for (int i = 0; i < 4; ++i)
    gp[i] = make_float4(lg[i*4]*inv, lg[i*4+1]*inv, lg[i*4+2]*inv, lg[i*4+3]*inv);
}

// ---------------- 256x256 8-phase bf16 GEMM, intra-phase overlap -----------
// Round-11 delta vs round-10 (ONE variable): intra-phase SCHED0 walls
// removed (QUAD tail, post-LOAD). Theory: phase = MFMA burst (564cy) +
// SERIAL LDS-read burst (~580cy) because the fences forbid the compiler
// from interleaving next-phase ds_read issue among the MFMA cluster (the
// WAR on shared frag regs frees each reg after its last MFMA read, so
// interleave is legal). Kept: BAR skeleton fences (SCHED0;s_barrier;SCHED0),
// WAITVM's post-asm SCHED0, setprio. Round-4's regression was confounded
// (peel + BAR-fence removal); this isolates intra-phase freedom only.
#define SCHED0 __builtin_amdgcn_sched_barrier(0)
#define BAR do { SCHED0; __builtin_amdgcn_s_barrier(); SCHED0; } while(0)
#define WAITVM(n) do { asm volatile("s_waitcnt vmcnt(" #n ")" ::: "memory"); SCHED0; } while(0)

// stage one 64-row chunk pair (half-tile) via walked pointers + k literal
#define STAGE_A(buf, h, klit) do { \
  async16(&As[(buf)*16384 + ((h)*128 + wave*8)*64],      wpA##h##0 + (klit)); \
  async16(&As[(buf)*16384 + ((h)*128 + 64 + wave*8)*64], wpA##h##1 + (klit)); \
  } while(0)

#define STAGE_B(buf, h, klit) do { \
  async16(&Bs[(buf)*16384 + ((h)*128 + wave*8)*64],      wpB##h##0 + (klit)); \
  async16(&Bs[(buf)*16384 + ((h)*128 + 64 + wave*8)*64], wpB##h##1 + (klit)); \
  } while(0)

#define LOAD_A(buf, MH) do { \
  _Pragma("unroll") for (int mi_ = 0; mi_ < 4; ++mi_) { \
    af[mi_][0] = *(const short8v*)(pa0 + (buf)*32768 + (MH)*8192 + mi_*2048); \
    af[mi_][1] = *(const short8v*)(pa1 + (buf)*32768 + (MH)*8192 + mi_*2048); \
  } } while(0)

#define LOAD_B(buf, NH) do { \
  _Pragma("unroll") for (int ni_ = 0; ni_ < 2; ++ni_) { \
    bf[NH][ni_][0] = *(const short8v*)(pb0 + (buf)*32768 + (NH)*4096 + ni_*2048); \
    bf[NH][ni_][1] = *(const short8v*)(pb1 + (buf)*32768 + (NH)*4096 + ni_*2048); \
  } } while(0)

#define QUAD(MH, NH) do { \
  __builtin_amdgcn_s_setprio(1); \
  _Pragma("unroll") for (int kk_ = 0; kk_ < 2; ++kk_) \
  _Pragma("unroll") for (int mi_ = 0; mi_ < 4; ++mi_) \
  _Pragma("unroll") for (int ni_ = 0; ni_ < 2; ++ni_) \
    acc[(MH)*4 + mi_][(NH)*2 + ni_] = __builtin_amdgcn_mfma_f32_16x16x32_bf16( \
        af[mi_][kk_], bf[NH][ni_][kk_], acc[(MH)*4 + mi_][(NH)*2 + ni_], 0, 0, 0); \
  __builtin_amdgcn_s_setprio(0); \
  } while(0)

__global__ __launch_bounds__(512, 2) void gemm8_kernel(
    const unsigned short* __restrict__ A, const unsigned short* __restrict__ Wt,
    const float* __restrict__ bias, unsigned short* __restrict__ Out,
    int K,
    long long strideA, long long strideW, long long strideB, long long strideO,
    const float* __restrict__ w3, float* __restrict__ eo_out)
{
  __shared__ unsigned short As[2 * 256 * 64];
  __shared__ unsigned short Bs[2 * 256 * 64];
  const int tid  = threadIdx.x;
  const int wave = tid >> 6, lane = tid & 63;
  const int wr = wave >> 2, wc = wave & 3;
  const int m0 = blockIdx.x * 256, n0 = blockIdx.y * 256;
  const int e  = blockIdx.z;
  const unsigned short* Ae = A + (size_t)e * strideA + (size_t)m0 * K;
  const unsigned short* We = Wt + (size_t)e * strideW + (size_t)n0 * K;
  const float* be = bias + (size_t)e * strideB;
  unsigned short* Oe = Out + (size_t)e * strideO;

  // staging lane geometry
  const int rsub = lane >> 3;                 // 0..7 row within 8-row block
  const int ssw  = ((lane & 7) ^ rsub) * 8;   // pre-swizzled global k-slot
  // fragment lane geometry
  const int fr  = lane & 15;
  const int kq  = lane >> 4;                  // 0..3
  const int fr7 = fr & 7;

  // --- precomputed LDS read bases (bytes): everything else is a literal ---
  const char* pa0 = (const char*)As + wr*16384 + fr*128 + ((kq ^ fr7) << 4);
  const char* pa1 = (const char*)As + wr*16384 + fr*128 + (((4 + kq) ^ fr7) << 4);
  const char* pb0 = (const char*)Bs + wc*8192  + fr*128 + ((kq ^ fr7) << 4);
  const char* pb1 = (const char*)Bs + wc*8192  + fr*128 + (((4 + kq) ^ fr7) << 4);

  // --- walked global staging pointers (one per 64-row chunk), +128 els/iter ---
  const unsigned short* wpA00 = Ae + (size_t)(      wave*8 + rsub) * K + ssw;
  const unsigned short* wpA01 = Ae + (size_t)( 64 + wave*8 + rsub) * K + ssw;
  const unsigned short* wpA10 = Ae + (size_t)(128 + wave*8 + rsub) * K + ssw;
  const unsigned short* wpA11 = Ae + (size_t)(192 + wave*8 + rsub) * K + ssw;
  const unsigned short* wpB00 = We + (size_t)(      wave*8 + rsub) * K + ssw;
  const unsigned short* wpB01 = We + (size_t)( 64 + wave*8 + rsub) * K + ssw;
  const unsigned short* wpB10 = We + (size_t)(128 + wave*8 + rsub) * K + ssw;
  const unsigned short* wpB11 = We + (size_t)(192 + wave*8 + rsub) * K + ssw;

  f32x4 acc[8][4] = {};
  short8v af[4][2];
  short8v bf[2][2][2];

  // ---- prologue: B0,A0 -> buf0; B1 -> buf1 (12 loads), drain to last 4 ----
  STAGE_B(0, 0, 0); STAGE_B(0, 1, 0);
  STAGE_A(0, 0, 0); STAGE_A(0, 1, 0);
  STAGE_B(1, 0, 64); STAGE_B(1, 1, 64);
  WAITVM(4);   // drains B0,A0 -> buf0 fully staged; B1 (4 loads) in flight
  BAR;

  const int NITER = K / 128;
  for (int j = 0; j < NITER; ++j) {
    const bool st = (j < NITER - 1);
    // P1 (boundary): read Q00(buf0) at top, compute it; then reads for P2
    LOAD_A(0, 0); LOAD_B(0, 0);
    QUAD(0, 0);
    LOAD_B(0, 1);
    STAGE_A(1, 0, 64);
    BAR;
    // P2: compute Q01; reads for P3 drain under it
    QUAD(0, 1);
    LOAD_A(0, 1);
    STAGE_A(1, 1, 64);
    BAR;
    // P3: compute Q10 (Q11 needs no new reads)
    QUAD(1, 0);
    if (st) STAGE_B(0, 0, 128);
    BAR;
    // P4: compute Q11; counted vmcnt certifies buf1 fully landed
    QUAD(1, 1);
    if (st) STAGE_B(0, 1, 128);
    if (st) { WAITVM(4); } else { WAITVM(0); }
    BAR;
    // P5 (boundary): read Q00(buf1) at top, compute it; then reads for P6
    LOAD_A(1, 0); LOAD_B(1, 0);
    QUAD(0, 0);
    LOAD_B(1, 1);
    if (st) STAGE_A(0, 0, 128);
    BAR;
    // P6: compute Q01; reads for P7 drain under it
    QUAD(0, 1);
    LOAD_A(1, 1);
    if (st) STAGE_A(0, 1, 128);
    BAR;
    // P7: compute Q10
    QUAD(1, 0);
    if (st) STAGE_B(1, 0, 192);
    BAR;
    // P8: compute Q11; counted vmcnt certifies buf0 fully landed
    QUAD(1, 1);
    if (st) { STAGE_B(1, 1, 192); WAITVM(4); }
    BAR;
    // advance staging pointers one iter (2 K-tiles = 128 elements)
    wpA00 += 128; wpA01 += 128; wpA10 += 128; wpA11 += 128;
    wpB00 += 128; wpB01 += 128; wpB10 += 128; wpB11 += 128;
  }

  // ---- epilogue ----
  if (w3 == nullptr) {
    // bias + relu + bf16 store
#pragma unroll
    for (int ni = 0; ni < 4; ++ni) {
      const int n = n0 + wc * 64 + ni * 16 + fr;
      const float bv = be[n];
#pragma unroll
      for (int mi = 0; mi < 8; ++mi) {
#pragma unroll
        for (int r = 0; r < 4; ++r) {
          const int m = m0 + wr * 128 + mi * 16 + kq * 4 + r;
          float v = acc[mi][ni][r] + bv;
          v = v > 0.f ? v : 0.f;
          Oe[(size_t)m * HID + n] = f2bf(v);
        }
      }
    }
  } else {
    // fused layer-3: p[m] = sum_n relu(acc+bias) * w3[n]; atomicAdd to eo
    const float* w3e = w3 + (size_t)e * HID;
    float bv[4], wv[4];
#pragma unroll
    for (int ni = 0; ni < 4; ++ni) {
      const int n = n0 + wc * 64 + ni * 16 + fr;
      bv[ni] = be[n];
      wv[ni] = w3e[n];
    }
    float* eoe = eo_out + (size_t)e * B_ROWS;
#pragma unroll
    for (int mi = 0; mi < 8; ++mi) {
#pragma unroll
      for (int r = 0; r < 4; ++r) {
        float p = 0.f;
#pragma unroll
        for (int ni = 0; ni < 4; ++ni) {
          float v = acc[mi][ni][r] + bv[ni];
          v = v > 0.f ? v : 0.f;
          p += v * wv[ni];
        }
        // reduce across the 16 fr-lanes (bits 0..3 of lane)
        p += __shfl_xor(p, 1, 64);
        p += __shfl_xor(p, 2, 64);
        p += __shfl_xor(p, 4, 64);
        p += __shfl_xor(p, 8, 64);
        if (fr == 0) {
          const int m = m0 + wr * 128 + mi * 16 + kq * 4 + r;
          atomicAdd(&eoe[m], p);
        }
      }
    }
  }
}

// ---------------- out[b] = sum_e gates[b][e] * (eo[e][b] + eb3[e]) ----------------
__global__ __launch_bounds__(256) void final_kernel(
    const float* __restrict__ gates, const float* __restrict__ eo,
    const float* __restrict__ eb3, float* __restrict__ out)
{
  const int b = blockIdx.x * blockDim.x + threadIdx.x;
  if (b >= B_ROWS) return;
  float s = 0.f;
#pragma unroll
  for (int e = 0; e < NEXP; ++e)
    s += gates[(size_t)b * 16 + e] * (eo[(size_t)e * B_ROWS + b] + eb3[e]);
  out[b] = s;
}

extern "C" void kernel_launch(void* const* d_in, const int* in_sizes, int n_in,
                              void* d_out, int out_size, void* d_ws, size_t ws_size,
                              hipStream_t stream)
{
  const float* user_emb = (const float*)d_in[0];
  const float* item_emb = (const float*)d_in[1];
  const float* f_i_1    = (const float*)d_in[2];
  const float* g_i_1    = (const float*)d_in[3];
  const float* f_i_2    = (const float*)d_in[4];
  const float* g_i_2    = (const float*)d_in[5];
  const float* f_i_3    = (const float*)d_in[6];
  const float* g_i_3    = (const float*)d_in[7];
  const float* cate     = (const float*)d_in[8];
  const float* gate_w1  = (const float*)d_in[9];
  const float* gate_b1  = (const float*)d_in[10];
  const float* gate_w2  = (const float*)d_in[11];
  const float* gate_b2  = (const float*)d_in[12];
  const float* ew1      = (const float*)d_in[13];
  const float* eb1      = (const float*)d_in[14];
  const float* ew2      = (const float*)d_in[15];
  const float* eb2      = (const float*)d_in[16];
  const float* ew3      = (const float*)d_in[17];
  const float* eb3      = (const float*)d_in[18];
  float* out = (float*)d_out;

  char* ws = (char*)d_ws;
  size_t off = 0;
  unsigned short* comb = (unsigned short*)(ws + off); off += (size_t)B_ROWS * KPAD * 2;
  unsigned short* w1t  = (unsigned short*)(ws + off); off += (size_t)NEXP * HID * KPAD * 2;
  unsigned short* w2t  = (unsigned short*)(ws + off); off += (size_t)NEXP * HID * HID * 2;
  unsigned short* h1   = (unsigned short*)(ws + off); off += (size_t)EG * B_ROWS * HID * 2;
  float* gates = (float*)(ws + off); off += (size_t)B_ROWS * NEXP * 4;
  float* eo    = (float*)(ws + off); off += (size_t)NEXP * B_ROWS * 4;

  // 0. zero eo accumulators (atomicAdd targets)
  hipMemsetAsync(eo, 0, (size_t)NEXP * B_ROWS * 4, stream);

  // 1. pack combined input (bf16, K zero-padded to 4224)
  {
    const long long total = (long long)B_ROWS * (KPAD / 8);
    const int blocks = (int)((total + 255) / 256);
    pack_kernel<<<blocks, 256, 0, stream>>>(user_emb, item_emb, f_i_1, g_i_1,
                                            f_i_2, g_i_2, f_i_3, g_i_3, cate, comb);
  }
  // 2. weight transposes to [E][N][K] bf16
  transpose_kernel<<<dim3(KPAD / 64, HID / 64, NEXP), 256, 0, stream>>>(ew1, w1t, KTOT, HID, KPAD);
  transpose_kernel<<<dim3(HID / 64, HID / 64, NEXP), 256, 0, stream>>>(ew2, w2t, HID, HID, HID);
  // 3. gates
  gate_kernel<<<B_ROWS / 256, 256, 0, stream>>>(cate, gate_w1, gate_b1, gate_w2, gate_b2, gates);

  // 4. expert groups: layer1 (K=4224) -> h1; layer2+layer3 fused (K=512) -> eo
  for (int g = 0; g < NGRP; ++g) {
    gemm8_kernel<<<dim3(B_ROWS / 256, HID / 256, EG), 512, 0, stream>>>(
        comb, w1t + (size_t)g * EG * HID * KPAD, eb1 + (size_t)g * EG * HID, h1,
        KPAD, 0LL, (long long)HID * KPAD, (long long)HID, (long long)B_ROWS * HID,
        nullptr, nullptr);
    gemm8_kernel<<<dim3(B_ROWS / 256, HID / 256, EG), 512, 0, stream>>>(
        h1, w2t + (size_t)g * EG * HID * HID, eb2 + (size_t)g * EG * HID, nullptr,
        HID, (long long)B_ROWS * HID, (long long)HID * HID, (long long)HID, 0LL,
        ew3 + (size_t)g * EG * HID, eo + (size_t)g * EG * B_ROWS);
  }
  // 5. combine
  final_kernel<<<B_ROWS / 256, 256, 0, stream>>>(gates, eo, eb3, out);
}

// Round 12
// 1294.960 us; speedup vs baseline: 1.1970x; 1.0120x over previous
//
#include <hip/hip_runtime.h>
#include <cstdint>
#include <cstddef>

#define B_ROWS 16384
#define NEXP 16
#define HID 512
#define KTOT 4112   // 8*512 + 16
#define KPAD 4224   // multiple of 128 (2 K-tiles of 64 per iter)
#define EG 4        // experts per group (fallback when ws is small)

typedef __attribute__((ext_vector_type(8))) short short8v;
typedef __attribute__((ext_vector_type(4))) float f32x4;

__device__ __forceinline__ float b2f(unsigned short s) {
  return __builtin_bit_cast(float, (unsigned)s << 16);
}
__device__ __forceinline__ unsigned short f2bf(float f) {
  unsigned u = __builtin_bit_cast(unsigned, f);
  return (unsigned short)((u + 0x7FFF + ((u >> 16) & 1)) >> 16);  // RNE
}

__device__ __forceinline__ void async16(void* lds, const void* g) {
  __builtin_amdgcn_global_load_lds((const __attribute__((address_space(1))) void*)g,
                                   (__attribute__((address_space(3))) void*)lds, 16, 0, 0);
}

// ---------------- pack combined -> bf16 [B][KPAD] ----------------
__global__ __launch_bounds__(256) void pack_kernel(
    const float* __restrict__ i0, const float* __restrict__ i1,
    const float* __restrict__ i2, const float* __restrict__ i3,
    const float* __restrict__ i4, const float* __restrict__ i5,
    const float* __restrict__ i6, const float* __restrict__ i7,
    const float* __restrict__ cate, unsigned short* __restrict__ comb)
{
  const long long idx = (long long)blockIdx.x * 256 + threadIdx.x;
  if (idx >= (long long)B_ROWS * (KPAD / 8)) return;
  const int b  = (int)(idx / (KPAD / 8));
  const int k8 = (int)(idx % (KPAD / 8));
  const int k  = k8 * 8;
  short8v v;
  if (k < 4096) {
    const int sel = k >> 9;
    const float* src = sel == 0 ? i0 : sel == 1 ? i1 : sel == 2 ? i2 : sel == 3 ? i3
                     : sel == 4 ? i4 : sel == 5 ? i5 : sel == 6 ? i6 : i7;
    src += (size_t)b * 512 + (k & 511);
    const float4 a = *(const float4*)(src);
    const float4 c = *(const float4*)(src + 4);
    v[0] = (short)f2bf(a.x); v[1] = (short)f2bf(a.y);
    v[2] = (short)f2bf(a.z); v[3] = (short)f2bf(a.w);
    v[4] = (short)f2bf(c.x); v[5] = (short)f2bf(c.y);
    v[6] = (short)f2bf(c.z); v[7] = (short)f2bf(c.w);
  } else if (k < KTOT) {
    const float* src = cate + (size_t)b * 16 + (k - 4096);
    const float4 a = *(const float4*)(src);
    const float4 c = *(const float4*)(src + 4);
    v[0] = (short)f2bf(a.x); v[1] = (short)f2bf(a.y);
    v[2] = (short)f2bf(a.z); v[3] = (short)f2bf(a.w);
    v[4] = (short)f2bf(c.x); v[5] = (short)f2bf(c.y);
    v[6] = (short)f2bf(c.z); v[7] = (short)f2bf(c.w);
  } else {
#pragma unroll
    for (int j = 0; j < 8; ++j) v[j] = 0;
  }
  *(short8v*)(comb + (size_t)b * KPAD + k) = v;
}

// ---------------- transpose f32 [E][Kin][N] -> bf16 [E][N][Kout] (zero-pad K) ----------------
__global__ __launch_bounds__(256) void transpose_kernel(
    const float* __restrict__ src, unsigned short* __restrict__ dst,
    int Kin, int N, int Kout)
{
  __shared__ unsigned short tile[64][68];
  const int e  = blockIdx.z;
  const int kt = blockIdx.x * 64;
  const int nt = blockIdx.y * 64;
  const int tx = threadIdx.x & 63, ty = threadIdx.x >> 6;
#pragma unroll
  for (int i = 0; i < 16; ++i) {
    const int kl = i * 4 + ty;
    const int kg = kt + kl;
    float v = (kg < Kin) ? src[((size_t)e * Kin + kg) * N + nt + tx] : 0.f;
    tile[kl][tx] = f2bf(v);
  }
  __syncthreads();
#pragma unroll
  for (int i = 0; i < 16; ++i) {
    const int nl = i * 4 + ty;
    const int kg = kt + tx;
    if (kg < Kout)
      dst[((size_t)e * N + nt + nl) * Kout + kg] = tile[tx][nl];
  }
}

// ---------------- gate ----------------
__global__ __launch_bounds__(256) void gate_kernel(
    const float* __restrict__ cate,
    const float* __restrict__ w1, const float* __restrict__ b1,
    const float* __restrict__ w2, const float* __restrict__ b2,
    float* __restrict__ gates)
{
  const int b = blockIdx.x * blockDim.x + threadIdx.x;
  if (b >= B_ROWS) return;
  float c[16];
  const float4* cp = (const float4*)(cate + (size_t)b * 16);
#pragma unroll
  for (int i = 0; i < 4; ++i) {
    float4 t = cp[i];
    c[i*4+0] = t.x; c[i*4+1] = t.y; c[i*4+2] = t.z; c[i*4+3] = t.w;
  }
  float h[8];
#pragma unroll
  for (int j = 0; j < 8; ++j) h[j] = b1[j];
#pragma unroll
  for (int i = 0; i < 16; ++i)
#pragma unroll
    for (int j = 0; j < 8; ++j) h[j] += c[i] * w1[i * 8 + j];
#pragma unroll
  for (int j = 0; j < 8; ++j) h[j] = h[j] > 0.f ? h[j] : 0.f;
  float lg[16];
#pragma unroll
  for (int k = 0; k < 16; ++k) lg[k] = b2[k];
#pragma unroll
  for (int j = 0; j < 8; ++j)
#pragma unroll
    for (int k = 0; k < 16; ++k) lg[k] += h[j] * w2[j * 16 + k];
  float mx = lg[0];
#pragma unroll
  for (int k = 1; k < 16; ++k) mx = fmaxf(mx, lg[k]);
  float s = 0.f;
#pragma unroll
  for (int k = 0; k < 16; ++k) { lg[k] = __expf(lg[k] - mx); s += lg[k]; }
  const float inv = 1.f / s;
  float4* gp = (float4*)(gates + (size_t)b * 16);
#pragma unroll
  for (int i = 0; i < 4; ++i)
    gp[i] = make_float4(lg[i*4]*inv, lg[i*4+1]*inv, lg[i*4+2]*inv, lg[i*4+3]*inv);
}

// ---------------- 256x256 8-phase bf16 GEMM (round-11 kernel, unchanged) ---
// Round-12 changes are LAUNCHER-ONLY (dispatch consolidation). Kernel is the
// round-11 best: 8-phase, software-pipelined ds_reads, zero-per-phase VALU
// (precomputed LDS bases + literal offsets, walked global staging pointers),
// counted vmcnt(4) at P4/P8, XOR swizzle (pre-swizzled source + swizzled read).
#define SCHED0 __builtin_amdgcn_sched_barrier(0)
#define BAR do { SCHED0; __builtin_amdgcn_s_barrier(); SCHED0; } while(0)
#define WAITVM(n) do { asm volatile("s_waitcnt vmcnt(" #n ")" ::: "memory"); SCHED0; } while(0)

#define STAGE_A(buf, h, klit) do { \
  async16(&As[(buf)*16384 + ((h)*128 + wave*8)*64],      wpA##h##0 + (klit)); \
  async16(&As[(buf)*16384 + ((h)*128 + 64 + wave*8)*64], wpA##h##1 + (klit)); \
  } while(0)

#define STAGE_B(buf, h, klit) do { \
  async16(&Bs[(buf)*16384 + ((h)*128 + wave*8)*64],      wpB##h##0 + (klit)); \
  async16(&Bs[(buf)*16384 + ((h)*128 + 64 + wave*8)*64], wpB##h##1 + (klit)); \
  } while(0)

#define LOAD_A(buf, MH) do { \
  _Pragma("unroll") for (int mi_ = 0; mi_ < 4; ++mi_) { \
    af[mi_][0] = *(const short8v*)(pa0 + (buf)*32768 + (MH)*8192 + mi_*2048); \
    af[mi_][1] = *(const short8v*)(pa1 + (buf)*32768 + (MH)*8192 + mi_*2048); \
  } } while(0)

#define LOAD_B(buf, NH) do { \
  _Pragma("unroll") for (int ni_ = 0; ni_ < 2; ++ni_) { \
    bf[NH][ni_][0] = *(const short8v*)(pb0 + (buf)*32768 + (NH)*4096 + ni_*2048); \
    bf[NH][ni_][1] = *(const short8v*)(pb1 + (buf)*32768 + (NH)*4096 + ni_*2048); \
  } } while(0)

#define QUAD(MH, NH) do { \
  __builtin_amdgcn_s_setprio(1); \
  _Pragma("unroll") for (int kk_ = 0; kk_ < 2; ++kk_) \
  _Pragma("unroll") for (int mi_ = 0; mi_ < 4; ++mi_) \
  _Pragma("unroll") for (int ni_ = 0; ni_ < 2; ++ni_) \
    acc[(MH)*4 + mi_][(NH)*2 + ni_] = __builtin_amdgcn_mfma_f32_16x16x32_bf16( \
        af[mi_][kk_], bf[NH][ni_][kk_], acc[(MH)*4 + mi_][(NH)*2 + ni_], 0, 0, 0); \
  __builtin_amdgcn_s_setprio(0); \
  } while(0)

__global__ __launch_bounds__(512, 2) void gemm8_kernel(
    const unsigned short* __restrict__ A, const unsigned short* __restrict__ Wt,
    const float* __restrict__ bias, unsigned short* __restrict__ Out,
    int K,
    long long strideA, long long strideW, long long strideB, long long strideO,
    const float* __restrict__ w3, float* __restrict__ eo_out)
{
  __shared__ unsigned short As[2 * 256 * 64];
  __shared__ unsigned short Bs[2 * 256 * 64];
  const int tid  = threadIdx.x;
  const int wave = tid >> 6, lane = tid & 63;
  const int wr = wave >> 2, wc = wave & 3;
  const int m0 = blockIdx.x * 256, n0 = blockIdx.y * 256;
  const int e  = blockIdx.z;
  const unsigned short* Ae = A + (size_t)e * strideA + (size_t)m0 * K;
  const unsigned short* We = Wt + (size_t)e * strideW + (size_t)n0 * K;
  const float* be = bias + (size_t)e * strideB;
  unsigned short* Oe = Out + (size_t)e * strideO;

  // staging lane geometry
  const int rsub = lane >> 3;                 // 0..7 row within 8-row block
  const int ssw  = ((lane & 7) ^ rsub) * 8;   // pre-swizzled global k-slot
  // fragment lane geometry
  const int fr  = lane & 15;
  const int kq  = lane >> 4;                  // 0..3
  const int fr7 = fr & 7;

  // --- precomputed LDS read bases (bytes): everything else is a literal ---
  const char* pa0 = (const char*)As + wr*16384 + fr*128 + ((kq ^ fr7) << 4);
  const char* pa1 = (const char*)As + wr*16384 + fr*128 + (((4 + kq) ^ fr7) << 4);
  const char* pb0 = (const char*)Bs + wc*8192  + fr*128 + ((kq ^ fr7) << 4);
  const char* pb1 = (const char*)Bs + wc*8192  + fr*128 + (((4 + kq) ^ fr7) << 4);

  // --- walked global staging pointers (one per 64-row chunk), +128 els/iter ---
  const unsigned short* wpA00 = Ae + (size_t)(      wave*8 + rsub) * K + ssw;
  const unsigned short* wpA01 = Ae + (size_t)( 64 + wave*8 + rsub) * K + ssw;
  const unsigned short* wpA10 = Ae + (size_t)(128 + wave*8 + rsub) * K + ssw;
  const unsigned short* wpA11 = Ae + (size_t)(192 + wave*8 + rsub) * K + ssw;
  const unsigned short* wpB00 = We + (size_t)(      wave*8 + rsub) * K + ssw;
  const unsigned short* wpB01 = We + (size_t)( 64 + wave*8 + rsub) * K + ssw;
  const unsigned short* wpB10 = We + (size_t)(128 + wave*8 + rsub) * K + ssw;
  const unsigned short* wpB11 = We + (size_t)(192 + wave*8 + rsub) * K + ssw;

  f32x4 acc[8][4] = {};
  short8v af[4][2];
  short8v bf[2][2][2];

  // ---- prologue: B0,A0 -> buf0; B1 -> buf1 (12 loads), drain to last 4 ----
  STAGE_B(0, 0, 0); STAGE_B(0, 1, 0);
  STAGE_A(0, 0, 0); STAGE_A(0, 1, 0);
  STAGE_B(1, 0, 64); STAGE_B(1, 1, 64);
  WAITVM(4);   // drains B0,A0 -> buf0 fully staged; B1 (4 loads) in flight
  BAR;

  const int NITER = K / 128;
  for (int j = 0; j < NITER; ++j) {
    const bool st = (j < NITER - 1);
    // P1 (boundary): read Q00(buf0) at top, compute it; then reads for P2
    LOAD_A(0, 0); LOAD_B(0, 0);
    QUAD(0, 0);
    LOAD_B(0, 1);
    STAGE_A(1, 0, 64);
    BAR;
    // P2: compute Q01; reads for P3 drain under it
    QUAD(0, 1);
    LOAD_A(0, 1);
    STAGE_A(1, 1, 64);
    BAR;
    // P3: compute Q10 (Q11 needs no new reads)
    QUAD(1, 0);
    if (st) STAGE_B(0, 0, 128);
    BAR;
    // P4: compute Q11; counted vmcnt certifies buf1 fully landed
    QUAD(1, 1);
    if (st) STAGE_B(0, 1, 128);
    if (st) { WAITVM(4); } else { WAITVM(0); }
    BAR;
    // P5 (boundary): read Q00(buf1) at top, compute it; then reads for P6
    LOAD_A(1, 0); LOAD_B(1, 0);
    QUAD(0, 0);
    LOAD_B(1, 1);
    if (st) STAGE_A(0, 0, 128);
    BAR;
    // P6: compute Q01; reads for P7 drain under it
    QUAD(0, 1);
    LOAD_A(1, 1);
    if (st) STAGE_A(0, 1, 128);
    BAR;
    // P7: compute Q10
    QUAD(1, 0);
    if (st) STAGE_B(1, 0, 192);
    BAR;
    // P8: compute Q11; counted vmcnt certifies buf0 fully landed
    QUAD(1, 1);
    if (st) { STAGE_B(1, 1, 192); WAITVM(4); }
    BAR;
    // advance staging pointers one iter (2 K-tiles = 128 elements)
    wpA00 += 128; wpA01 += 128; wpA10 += 128; wpA11 += 128;
    wpB00 += 128; wpB01 += 128; wpB10 += 128; wpB11 += 128;
  }

  // ---- epilogue ----
  if (w3 == nullptr) {
    // bias + relu + bf16 store
#pragma unroll
    for (int ni = 0; ni < 4; ++ni) {
      const int n = n0 + wc * 64 + ni * 16 + fr;
      const float bv = be[n];
#pragma unroll
      for (int mi = 0; mi < 8; ++mi) {
#pragma unroll
        for (int r = 0; r < 4; ++r) {
          const int m = m0 + wr * 128 + mi * 16 + kq * 4 + r;
          float v = acc[mi][ni][r] + bv;
          v = v > 0.f ? v : 0.f;
          Oe[(size_t)m * HID + n] = f2bf(v);
        }
      }
    }
  } else {
    // fused layer-3: p[m] = sum_n relu(acc+bias) * w3[n]; atomicAdd to eo
    const float* w3e = w3 + (size_t)e * HID;
    float bv[4], wv[4];
#pragma unroll
    for (int ni = 0; ni < 4; ++ni) {
      const int n = n0 + wc * 64 + ni * 16 + fr;
      bv[ni] = be[n];
      wv[ni] = w3e[n];
    }
    float* eoe = eo_out + (size_t)e * B_ROWS;
#pragma unroll
    for (int mi = 0; mi < 8; ++mi) {
#pragma unroll
      for (int r = 0; r < 4; ++r) {
        float p = 0.f;
#pragma unroll
        for (int ni = 0; ni < 4; ++ni) {
          float v = acc[mi][ni][r] + bv[ni];
          v = v > 0.f ? v : 0.f;
          p += v * wv[ni];
        }
        // reduce across the 16 fr-lanes (bits 0..3 of lane)
        p += __shfl_xor(p, 1, 64);
        p += __shfl_xor(p, 2, 64);
        p += __shfl_xor(p, 4, 64);
        p += __shfl_xor(p, 8, 64);
        if (fr == 0) {
          const int m = m0 + wr * 128 + mi * 16 + kq * 4 + r;
          atomicAdd(&eoe[m], p);
        }
      }
    }
  }
}

// ---------------- out[b] = sum_e gates[b][e] * (eo[e][b] + eb3[e]) ----------------
__global__ __launch_bounds__(256) void final_kernel(
    const float* __restrict__ gates, const float* __restrict__ eo,
    const float* __restrict__ eb3, float* __restrict__ out)
{
  const int b = blockIdx.x * blockDim.x + threadIdx.x;
  if (b >= B_ROWS) return;
  float s = 0.f;
#pragma unroll
  for (int e = 0; e < NEXP; ++e)
    s += gates[(size_t)b * 16 + e] * (eo[(size_t)e * B_ROWS + b] + eb3[e]);
  out[b] = s;
}

extern "C" void kernel_launch(void* const* d_in, const int* in_sizes, int n_in,
                              void* d_out, int out_size, void* d_ws, size_t ws_size,
                              hipStream_t stream)
{
  const float* user_emb = (const float*)d_in[0];
  const float* item_emb = (const float*)d_in[1];
  const float* f_i_1    = (const float*)d_in[2];
  const float* g_i_1    = (const float*)d_in[3];
  const float* f_i_2    = (const float*)d_in[4];
  const float* g_i_2    = (const float*)d_in[5];
  const float* f_i_3    = (const float*)d_in[6];
  const float* g_i_3    = (const float*)d_in[7];
  const float* cate     = (const float*)d_in[8];
  const float* gate_w1  = (const float*)d_in[9];
  const float* gate_b1  = (const float*)d_in[10];
  const float* gate_w2  = (const float*)d_in[11];
  const float* gate_b2  = (const float*)d_in[12];
  const float* ew1      = (const float*)d_in[13];
  const float* eb1      = (const float*)d_in[14];
  const float* ew2      = (const float*)d_in[15];
  const float* eb2      = (const float*)d_in[16];
  const float* ew3      = (const float*)d_in[17];
  const float* eb3      = (const float*)d_in[18];
  float* out = (float*)d_out;

  // Workspace layout. Prefer ONE expert group (all 16 experts per GEMM
  // dispatch — fewest dispatch boundaries); fall back to 4 groups of 4 if
  // d_ws can't hold the full h1. Deterministic given ws_size (graph-safe).
  const size_t sz_comb  = (size_t)B_ROWS * KPAD * 2;
  const size_t sz_w1t   = (size_t)NEXP * HID * KPAD * 2;
  const size_t sz_w2t   = (size_t)NEXP * HID * HID * 2;
  const size_t sz_gates = (size_t)B_ROWS * NEXP * 4;
  const size_t sz_eo    = (size_t)NEXP * B_ROWS * 4;
  const size_t fixed    = sz_comb + sz_w1t + sz_w2t + sz_gates + sz_eo;
  const size_t sz_h1_full = (size_t)NEXP * B_ROWS * HID * 2;
  const int eg   = (ws_size >= fixed + sz_h1_full) ? NEXP : EG;
  const int ngrp = NEXP / eg;
  const size_t sz_h1 = (size_t)eg * B_ROWS * HID * 2;

  char* ws = (char*)d_ws;
  size_t off = 0;
  unsigned short* comb = (unsigned short*)(ws + off); off += sz_comb;
  unsigned short* w1t  = (unsigned short*)(ws + off); off += sz_w1t;
  unsigned short* w2t  = (unsigned short*)(ws + off); off += sz_w2t;
  unsigned short* h1   = (unsigned short*)(ws + off); off += sz_h1;
  float* gates = (float*)(ws + off); off += sz_gates;
  float* eo    = (float*)(ws + off); off += sz_eo;

  // 0. zero eo accumulators (atomicAdd targets)
  hipMemsetAsync(eo, 0, sz_eo, stream);

  // 1. pack combined input (bf16, K zero-padded to 4224)
  {
    const long long total = (long long)B_ROWS * (KPAD / 8);
    const int blocks = (int)((total + 255) / 256);
    pack_kernel<<<blocks, 256, 0, stream>>>(user_emb, item_emb, f_i_1, g_i_1,
                                            f_i_2, g_i_2, f_i_3, g_i_3, cate, comb);
  }
  // 2. weight transposes to [E][N][K] bf16
  transpose_kernel<<<dim3(KPAD / 64, HID / 64, NEXP), 256, 0, stream>>>(ew1, w1t, KTOT, HID, KPAD);
  transpose_kernel<<<dim3(HID / 64, HID / 64, NEXP), 256, 0, stream>>>(ew2, w2t, HID, HID, HID);
  // 3. gates
  gate_kernel<<<B_ROWS / 256, 256, 0, stream>>>(cate, gate_w1, gate_b1, gate_w2, gate_b2, gates);

  // 4. expert groups: layer1 (K=4224) -> h1; layer2+layer3 fused (K=512) -> eo
  for (int g = 0; g < ngrp; ++g) {
    gemm8_kernel<<<dim3(B_ROWS / 256, HID / 256, eg), 512, 0, stream>>>(
        comb, w1t + (size_t)g * eg * HID * KPAD, eb1 + (size_t)g * eg * HID, h1,
        KPAD, 0LL, (long long)HID * KPAD, (long long)HID, (long long)B_ROWS * HID,
        nullptr, nullptr);
    gemm8_kernel<<<dim3(B_ROWS / 256, HID / 256, eg), 512, 0, stream>>>(
        h1, w2t + (size_t)g * eg * HID * HID, eb2 + (size_t)g * eg * HID, nullptr,
        HID, (long long)B_ROWS * HID, (long long)HID * HID, (long long)HID, 0LL,
        ew3 + (size_t)g * eg * HID, eo + (size_t)g * eg * B_ROWS);
  }
  // 5. combine
  final_kernel<<<B_ROWS / 256, 256, 0, stream>>>(gates, eo, eb3, out);
}

// Round 14
// 1291.841 us; speedup vs baseline: 1.1999x; 1.0024x over previous
//
#include <hip/hip_runtime.h>
#include <cstdint>
#include <cstddef>

#define B_ROWS 16384
#define NEXP 16
#define HID 512
#define KTOT 4112   // 8*512 + 16
#define KPAD 4224   // multiple of 128 (2 K-tiles of 64 per iter)
#define EG 4        // experts per group (fallback when ws is small)

typedef __attribute__((ext_vector_type(8))) short short8v;
typedef __attribute__((ext_vector_type(4))) float f32x4;

__device__ __forceinline__ float b2f(unsigned short s) {
  return __builtin_bit_cast(float, (unsigned)s << 16);
}
__device__ __forceinline__ unsigned short f2bf(float f) {
  unsigned u = __builtin_bit_cast(unsigned, f);
  return (unsigned short)((u + 0x7FFF + ((u >> 16) & 1)) >> 16);  // RNE
}

__device__ __forceinline__ void async16(void* lds, const void* g) {
  __builtin_amdgcn_global_load_lds((const __attribute__((address_space(1))) void*)g,
                                   (__attribute__((address_space(3))) void*)lds, 16, 0, 0);
}

// ---------------- pack combined -> bf16 [B][KPAD] ----------------
__global__ __launch_bounds__(256) void pack_kernel(
    const float* __restrict__ i0, const float* __restrict__ i1,
    const float* __restrict__ i2, const float* __restrict__ i3,
    const float* __restrict__ i4, const float* __restrict__ i5,
    const float* __restrict__ i6, const float* __restrict__ i7,
    const float* __restrict__ cate, unsigned short* __restrict__ comb)
{
  const long long idx = (long long)blockIdx.x * 256 + threadIdx.x;
  if (idx >= (long long)B_ROWS * (KPAD / 8)) return;
  const int b  = (int)(idx / (KPAD / 8));
  const int k8 = (int)(idx % (KPAD / 8));
  const int k  = k8 * 8;
  short8v v;
  if (k < 4096) {
    const int sel = k >> 9;
    const float* src = sel == 0 ? i0 : sel == 1 ? i1 : sel == 2 ? i2 : sel == 3 ? i3
                     : sel == 4 ? i4 : sel == 5 ? i5 : sel == 6 ? i6 : i7;
    src += (size_t)b * 512 + (k & 511);
    const float4 a = *(const float4*)(src);
    const float4 c = *(const float4*)(src + 4);
    v[0] = (short)f2bf(a.x); v[1] = (short)f2bf(a.y);
    v[2] = (short)f2bf(a.z); v[3] = (short)f2bf(a.w);
    v[4] = (short)f2bf(c.x); v[5] = (short)f2bf(c.y);
    v[6] = (short)f2bf(c.z); v[7] = (short)f2bf(c.w);
  } else if (k < KTOT) {
    const float* src = cate + (size_t)b * 16 + (k - 4096);
    const float4 a = *(const float4*)(src);
    const float4 c = *(const float4*)(src + 4);
    v[0] = (short)f2bf(a.x); v[1] = (short)f2bf(a.y);
    v[2] = (short)f2bf(a.z); v[3] = (short)f2bf(a.w);
    v[4] = (short)f2bf(c.x); v[5] = (short)f2bf(c.y);
    v[6] = (short)f2bf(c.z); v[7] = (short)f2bf(c.w);
  } else {
#pragma unroll
    for (int j = 0; j < 8; ++j) v[j] = 0;
  }
  *(short8v*)(comb + (size_t)b * KPAD + k) = v;
}

// ---------------- transpose f32 [E][Kin][N] -> bf16 [E][N][Kout] (zero-pad K) ----------------
__global__ __launch_bounds__(256) void transpose_kernel(
    const float* __restrict__ src, unsigned short* __restrict__ dst,
    int Kin, int N, int Kout)
{
  __shared__ unsigned short tile[64][68];
  const int e  = blockIdx.z;
  const int kt = blockIdx.x * 64;
  const int nt = blockIdx.y * 64;
  const int tx = threadIdx.x & 63, ty = threadIdx.x >> 6;
#pragma unroll
  for (int i = 0; i < 16; ++i) {
    const int kl = i * 4 + ty;
    const int kg = kt + kl;
    float v = (kg < Kin) ? src[((size_t)e * Kin + kg) * N + nt + tx] : 0.f;
    tile[kl][tx] = f2bf(v);
  }
  __syncthreads();
#pragma unroll
  for (int i = 0; i < 16; ++i) {
    const int nl = i * 4 + ty;
    const int kg = kt + tx;
    if (kg < Kout)
      dst[((size_t)e * N + nt + nl) * Kout + kg] = tile[tx][nl];
  }
}

// ---------------- gate ----------------
__global__ __launch_bounds__(256) void gate_kernel(
    const float* __restrict__ cate,
    const float* __restrict__ w1, const float* __restrict__ b1,
    const float* __restrict__ w2, const float* __restrict__ b2,
    float* __restrict__ gates)
{
  const int b = blockIdx.x * blockDim.x + threadIdx.x;
  if (b >= B_ROWS) return;
  float c[16];
  const float4* cp = (const float4*)(cate + (size_t)b * 16);
#pragma unroll
  for (int i = 0; i < 4; ++i) {
    float4 t = cp[i];
    c[i*4+0] = t.x; c[i*4+1] = t.y; c[i*4+2] = t.z; c[i*4+3] = t.w;
  }
  float h[8];
#pragma unroll
  for (int j = 0; j < 8; ++j) h[j] = b1[j];
#pragma unroll
  for (int i = 0; i < 16; ++i)
#pragma unroll
    for (int j = 0; j < 8; ++j) h[j] += c[i] * w1[i * 8 + j];
#pragma unroll
  for (int j = 0; j < 8; ++j) h[j] = h[j] > 0.f ? h[j] : 0.f;
  float lg[16];
#pragma unroll
  for (int k = 0; k < 16; ++k) lg[k] = b2[k];
#pragma unroll
  for (int j = 0; j < 8; ++j)
#pragma unroll
    for (int k = 0; k < 16; ++k) lg[k] += h[j] * w2[j * 16 + k];
  float mx = lg[0];
#pragma unroll
  for (int k = 1; k < 16; ++k) mx = fmaxf(mx, lg[k]);
  float s = 0.f;
#pragma unroll
  for (int k = 0; k < 16; ++k) { lg[k] = __expf(lg[k] - mx); s += lg[k]; }
  const float inv = 1.f / s;
  float4* gp = (float4*)(gates + (size_t)b * 16);
#pragma unroll
  for (int i = 0; i < 4; ++i)
    gp[i] = make_float4(lg[i*4]*inv, lg[i*4+1]*inv, lg[i*4+2]*inv, lg[i*4+3]*inv);
}

// ---------------- 256x256 bf16 GEMM, 4-phase schedule (race-fixed) -------
// Round-14 = round-13's 4-phase with the cross-wave race FIXED: round 13
// issued reads of a newly-certified buffer after WAITVM(4) but BEFORE the
// barrier — vmcnt certifies only the issuing wave's staging loads, while the
// rows it reads were staged by ALL 8 waves. All such reads now sit AFTER the
// certifying barrier (top of the next phase, r8's boundary-phase pattern):
//  P1(bnd): rd A00,B00,B01; Q00,Q01; rd A01; stage A_v;            BAR
//  P2:      Q10,Q11;        stage B_u2;       WAITVM(4);           BAR
//  P3(bnd): rd A10,B10,B11; Q00,Q01; rd A11; stage A_u2;           BAR
//  P4:      Q10,Q11;        stage B_v2;       WAITVM(4);           BAR
// Ledger (steady state, per wave): enter P1 with 4 in flight (B_v);
// P1 +A_v=8; P2 +B_u2=12, WAITVM(4) drains B_v+A_v => buf1 certified
// BEFORE P2's BAR => P3's reads safe across waves; P3 +A_u2=8;
// P4 +B_v2=12, WAITVM(4) drains B_u2+A_u2 => buf0 certified for next P1.
// Write-after-read: every STAGE target's last ds_read completes before its
// reader-phase's MFMAs (compiler lgkm), >=1 barrier before the overwrite.
#define SCHED0 __builtin_amdgcn_sched_barrier(0)
#define BAR do { SCHED0; __builtin_amdgcn_s_barrier(); SCHED0; } while(0)
#define WAITVM(n) do { asm volatile("s_waitcnt vmcnt(" #n ")" ::: "memory"); SCHED0; } while(0)

#define STAGE_A(buf, h, klit) do { \
  async16(&As[(buf)*16384 + ((h)*128 + wave*8)*64],      wpA##h##0 + (klit)); \
  async16(&As[(buf)*16384 + ((h)*128 + 64 + wave*8)*64], wpA##h##1 + (klit)); \
  } while(0)

#define STAGE_B(buf, h, klit) do { \
  async16(&Bs[(buf)*16384 + ((h)*128 + wave*8)*64],      wpB##h##0 + (klit)); \
  async16(&Bs[(buf)*16384 + ((h)*128 + 64 + wave*8)*64], wpB##h##1 + (klit)); \
  } while(0)

#define LOAD_A(buf, MH) do { \
  _Pragma("unroll") for (int mi_ = 0; mi_ < 4; ++mi_) { \
    af[mi_][0] = *(const short8v*)(pa0 + (buf)*32768 + (MH)*8192 + mi_*2048); \
    af[mi_][1] = *(const short8v*)(pa1 + (buf)*32768 + (MH)*8192 + mi_*2048); \
  } } while(0)

#define LOAD_B(buf, NH) do { \
  _Pragma("unroll") for (int ni_ = 0; ni_ < 2; ++ni_) { \
    bf[NH][ni_][0] = *(const short8v*)(pb0 + (buf)*32768 + (NH)*4096 + ni_*2048); \
    bf[NH][ni_][1] = *(const short8v*)(pb1 + (buf)*32768 + (NH)*4096 + ni_*2048); \
  } } while(0)

#define QUAD(MH, NH) do { \
  __builtin_amdgcn_s_setprio(1); \
  _Pragma("unroll") for (int kk_ = 0; kk_ < 2; ++kk_) \
  _Pragma("unroll") for (int mi_ = 0; mi_ < 4; ++mi_) \
  _Pragma("unroll") for (int ni_ = 0; ni_ < 2; ++ni_) \
    acc[(MH)*4 + mi_][(NH)*2 + ni_] = __builtin_amdgcn_mfma_f32_16x16x32_bf16( \
        af[mi_][kk_], bf[NH][ni_][kk_], acc[(MH)*4 + mi_][(NH)*2 + ni_], 0, 0, 0); \
  __builtin_amdgcn_s_setprio(0); \
  } while(0)

__global__ __launch_bounds__(512, 2) void gemm8_kernel(
    const unsigned short* __restrict__ A, const unsigned short* __restrict__ Wt,
    const float* __restrict__ bias, unsigned short* __restrict__ Out,
    int K,
    long long strideA, long long strideW, long long strideB, long long strideO,
    const float* __restrict__ w3, float* __restrict__ eo_out)
{
  __shared__ unsigned short As[2 * 256 * 64];
  __shared__ unsigned short Bs[2 * 256 * 64];
  const int tid  = threadIdx.x;
  const int wave = tid >> 6, lane = tid & 63;
  const int wr = wave >> 2, wc = wave & 3;
  const int m0 = blockIdx.x * 256, n0 = blockIdx.y * 256;
  const int e  = blockIdx.z;
  const unsigned short* Ae = A + (size_t)e * strideA + (size_t)m0 * K;
  const unsigned short* We = Wt + (size_t)e * strideW + (size_t)n0 * K;
  const float* be = bias + (size_t)e * strideB;
  unsigned short* Oe = Out + (size_t)e * strideO;

  // staging lane geometry
  const int rsub = lane >> 3;                 // 0..7 row within 8-row block
  const int ssw  = ((lane & 7) ^ rsub) * 8;   // pre-swizzled global k-slot
  // fragment lane geometry
  const int fr  = lane & 15;
  const int kq  = lane >> 4;                  // 0..3
  const int fr7 = fr & 7;

  // --- precomputed LDS read bases (bytes): everything else is a literal ---
  const char* pa0 = (const char*)As + wr*16384 + fr*128 + ((kq ^ fr7) << 4);
  const char* pa1 = (const char*)As + wr*16384 + fr*128 + (((4 + kq) ^ fr7) << 4);
  const char* pb0 = (const char*)Bs + wc*8192  + fr*128 + ((kq ^ fr7) << 4);
  const char* pb1 = (const char*)Bs + wc*8192  + fr*128 + (((4 + kq) ^ fr7) << 4);

  // --- walked global staging pointers (one per 64-row chunk), +128 els/iter ---
  const unsigned short* wpA00 = Ae + (size_t)(      wave*8 + rsub) * K + ssw;
  const unsigned short* wpA01 = Ae + (size_t)( 64 + wave*8 + rsub) * K + ssw;
  const unsigned short* wpA10 = Ae + (size_t)(128 + wave*8 + rsub) * K + ssw;
  const unsigned short* wpA11 = Ae + (size_t)(192 + wave*8 + rsub) * K + ssw;
  const unsigned short* wpB00 = We + (size_t)(      wave*8 + rsub) * K + ssw;
  const unsigned short* wpB01 = We + (size_t)( 64 + wave*8 + rsub) * K + ssw;
  const unsigned short* wpB10 = We + (size_t)(128 + wave*8 + rsub) * K + ssw;
  const unsigned short* wpB11 = We + (size_t)(192 + wave*8 + rsub) * K + ssw;

  f32x4 acc[8][4] = {};
  short8v af[4][2];
  short8v bf[2][2][2];

  // ---- prologue: B_u,A_u -> buf0; B_v -> buf1; cert buf0; BAR ----
  STAGE_B(0, 0, 0); STAGE_B(0, 1, 0);
  STAGE_A(0, 0, 0); STAGE_A(0, 1, 0);
  STAGE_B(1, 0, 64); STAGE_B(1, 1, 64);
  WAITVM(4);   // drains B_u,A_u -> buf0 fully staged (per wave); B_v in flight
  BAR;         // all waves certified -> buf0 safe to read

  const int NITER = K / 128;
  for (int j = 0; j < NITER; ++j) {
    const bool st = (j < NITER - 1);
    // P1 (boundary): reads of buf0 AFTER the certifying barrier
    LOAD_A(0, 0); LOAD_B(0, 0); LOAD_B(0, 1);
    QUAD(0, 0);
    QUAD(0, 1);
    LOAD_A(0, 1);
    STAGE_A(1, 0, 64); STAGE_A(1, 1, 64);
    BAR;
    // P2: finish buf0; stage B_u2; certify buf1 (WAITVM before BAR)
    QUAD(1, 0);
    QUAD(1, 1);
    if (st) { STAGE_B(0, 0, 128); STAGE_B(0, 1, 128); WAITVM(4); }
    else    { WAITVM(0); }
    BAR;
    // P3 (boundary): reads of buf1 AFTER the certifying barrier
    LOAD_A(1, 0); LOAD_B(1, 0); LOAD_B(1, 1);
    QUAD(0, 0);
    QUAD(0, 1);
    LOAD_A(1, 1);
    if (st) { STAGE_A(0, 0, 128); STAGE_A(0, 1, 128); }
    BAR;
    // P4: finish buf1; stage B_v2; certify buf0 (WAITVM before BAR)
    QUAD(1, 0);
    QUAD(1, 1);
    if (st) { STAGE_B(1, 0, 192); STAGE_B(1, 1, 192); WAITVM(4); }
    BAR;
    // advance staging pointers one iter (2 K-tiles = 128 elements)
    wpA00 += 128; wpA01 += 128; wpA10 += 128; wpA11 += 128;
    wpB00 += 128; wpB01 += 128; wpB10 += 128; wpB11 += 128;
  }

  // ---- epilogue ----
  if (w3 == nullptr) {
    // bias + relu + bf16 store
#pragma unroll
    for (int ni = 0; ni < 4; ++ni) {
      const int n = n0 + wc * 64 + ni * 16 + fr;
      const float bv = be[n];
#pragma unroll
      for (int mi = 0; mi < 8; ++mi) {
#pragma unroll
        for (int r = 0; r < 4; ++r) {
          const int m = m0 + wr * 128 + mi * 16 + kq * 4 + r;
          float v = acc[mi][ni][r] + bv;
          v = v > 0.f ? v : 0.f;
          Oe[(size_t)m * HID + n] = f2bf(v);
        }
      }
    }
  } else {
    // fused layer-3: p[m] = sum_n relu(acc+bias) * w3[n]; atomicAdd to eo
    const float* w3e = w3 + (size_t)e * HID;
    float bv[4], wv[4];
#pragma unroll
    for (int ni = 0; ni < 4; ++ni) {
      const int n = n0 + wc * 64 + ni * 16 + fr;
      bv[ni] = be[n];
      wv[ni] = w3e[n];
    }
    float* eoe = eo_out + (size_t)e * B_ROWS;
#pragma unroll
    for (int mi = 0; mi < 8; ++mi) {
#pragma unroll
      for (int r = 0; r < 4; ++r) {
        float p = 0.f;
#pragma unroll
        for (int ni = 0; ni < 4; ++ni) {
          float v = acc[mi][ni][r] + bv[ni];
          v = v > 0.f ? v : 0.f;
          p += v * wv[ni];
        }
        // reduce across the 16 fr-lanes (bits 0..3 of lane)
        p += __shfl_xor(p, 1, 64);
        p += __shfl_xor(p, 2, 64);
        p += __shfl_xor(p, 4, 64);
        p += __shfl_xor(p, 8, 64);
        if (fr == 0) {
          const int m = m0 + wr * 128 + mi * 16 + kq * 4 + r;
          atomicAdd(&eoe[m], p);
        }
      }
    }
  }
}

// ---------------- out[b] = sum_e gates[b][e] * (eo[e][b] + eb3[e]) ----------------
__global__ __launch_bounds__(256) void final_kernel(
    const float* __restrict__ gates, const float* __restrict__ eo,
    const float* __restrict__ eb3, float* __restrict__ out)
{
  const int b = blockIdx.x * blockDim.x + threadIdx.x;
  if (b >= B_ROWS) return;
  float s = 0.f;
#pragma unroll
  for (int e = 0; e < NEXP; ++e)
    s += gates[(size_t)b * 16 + e] * (eo[(size_t)e * B_ROWS + b] + eb3[e]);
  out[b] = s;
}

extern "C" void kernel_launch(void* const* d_in, const int* in_sizes, int n_in,
                              void* d_out, int out_size, void* d_ws, size_t ws_size,
                              hipStream_t stream)
{
  const float* user_emb = (const float*)d_in[0];
  const float* item_emb = (const float*)d_in[1];
  const float* f_i_1    = (const float*)d_in[2];
  const float* g_i_1    = (const float*)d_in[3];
  const float* f_i_2    = (const float*)d_in[4];
  const float* g_i_2    = (const float*)d_in[5];
  const float* f_i_3    = (const float*)d_in[6];
  const float* g_i_3    = (const float*)d_in[7];
  const float* cate     = (const float*)d_in[8];
  const float* gate_w1  = (const float*)d_in[9];
  const float* gate_b1  = (const float*)d_in[10];
  const float* gate_w2  = (const float*)d_in[11];
  const float* gate_b2  = (const float*)d_in[12];
  const float* ew1      = (const float*)d_in[13];
  const float* eb1      = (const float*)d_in[14];
  const float* ew2      = (const float*)d_in[15];
  const float* eb2      = (const float*)d_in[16];
  const float* ew3      = (const float*)d_in[17];
  const float* eb3      = (const float*)d_in[18];
  float* out = (float*)d_out;

  // Workspace layout. Prefer ONE expert group (all 16 experts per GEMM
  // dispatch — fewest dispatch boundaries); fall back to 4 groups of 4 if
  // d_ws can't hold the full h1. Deterministic given ws_size (graph-safe).
  const size_t sz_comb  = (size_t)B_ROWS * KPAD * 2;
  const size_t sz_w1t   = (size_t)NEXP * HID * KPAD * 2;
  const size_t sz_w2t   = (size_t)NEXP * HID * HID * 2;
  const size_t sz_gates = (size_t)B_ROWS * NEXP * 4;
  const size_t sz_eo    = (size_t)NEXP * B_ROWS * 4;
  const size_t fixed    = sz_comb + sz_w1t + sz_w2t + sz_gates + sz_eo;
  const size_t sz_h1_full = (size_t)NEXP * B_ROWS * HID * 2;
  const int eg   = (ws_size >= fixed + sz_h1_full) ? NEXP : EG;
  const int ngrp = NEXP / eg;
  const size_t sz_h1 = (size_t)eg * B_ROWS * HID * 2;

  char* ws = (char*)d_ws;
  size_t off = 0;
  unsigned short* comb = (unsigned short*)(ws + off); off += sz_comb;
  unsigned short* w1t  = (unsigned short*)(ws + off); off += sz_w1t;
  unsigned short* w2t  = (unsigned short*)(ws + off); off += sz_w2t;
  unsigned short* h1   = (unsigned short*)(ws + off); off += sz_h1;
  float* gates = (float*)(ws + off); off += sz_gates;
  float* eo    = (float*)(ws + off); off += sz_eo;

  // 0. zero eo accumulators (atomicAdd targets)
  hipMemsetAsync(eo, 0, sz_eo, stream);

  // 1. pack combined input (bf16, K zero-padded to 4224)
  {
    const long long total = (long long)B_ROWS * (KPAD / 8);
    const int blocks = (int)((total + 255) / 256);
    pack_kernel<<<blocks, 256, 0, stream>>>(user_emb, item_emb, f_i_1, g_i_1,
                                            f_i_2, g_i_2, f_i_3, g_i_3, cate, comb);
  }
  // 2. weight transposes to [E][N][K] bf16
  transpose_kernel<<<dim3(KPAD / 64, HID / 64, NEXP), 256, 0, stream>>>(ew1, w1t, KTOT, HID, KPAD);
  transpose_kernel<<<dim3(HID / 64, HID / 64, NEXP), 256, 0, stream>>>(ew2, w2t, HID, HID, HID);
  // 3. gates
  gate_kernel<<<B_ROWS / 256, 256, 0, stream>>>(cate, gate_w1, gate_b1, gate_w2, gate_b2, gates);

  // 4. expert groups: layer1 (K=4224) -> h1; layer2+layer3 fused (K=512) -> eo
  for (int g = 0; g < ngrp; ++g) {
    gemm8_kernel<<<dim3(B_ROWS / 256, HID / 256, eg), 512, 0, stream>>>(
        comb, w1t + (size_t)g * eg * HID * KPAD, eb1 + (size_t)g * eg * HID, h1,
        KPAD, 0LL, (long long)HID * KPAD, (long long)HID, (long long)B_ROWS * HID,
        nullptr, nullptr);
    gemm8_kernel<<<dim3(B_ROWS / 256, HID / 256, eg), 512, 0, stream>>>(
        h1, w2t + (size_t)g * eg * HID * HID, eb2 + (size_t)g * eg * HID, nullptr,
        HID, (long long)B_ROWS * HID, (long long)HID * HID, (long long)HID, 0LL,
        ew3 + (size_t)g * eg * HID, eo + (size_t)g * eg * B_ROWS);
  }
  // 5. combine
  final_kernel<<<B_ROWS / 256, 256, 0, stream>>>(gates, eo, eb3, out);
}